// Round 8
// baseline (386.610 us; speedup 1.0000x reference)
//
#include <hip/hip_runtime.h>

#define HH 8
#define FOUT 128
#define DIN 64
#define NCOL 160          // 128 h cols + 24 logit cols + 8 pad (10 MFMA j-tiles)
#define NSLOPE 0.2f
#define HR 4096           // dst-range per CSR bin (16 KB LDS histogram)
#define CHUNKN 8          // edge-slice chunks per bin

typedef __attribute__((ext_vector_type(8))) short bf16x8;
typedef __attribute__((ext_vector_type(4))) float f32x4;

__device__ __forceinline__ float fast_rcp(float x) { return __builtin_amdgcn_rcpf(x); }

__device__ __forceinline__ float fast_tanh(float x) {
    float ax = fabsf(x);
    float e = __expf(-2.f * ax);
    float r = (1.f - e) * fast_rcp(1.f + e);
    return x >= 0.f ? r : -r;
}

__device__ __forceinline__ unsigned short f2bf(float f) {
    unsigned u = __builtin_bit_cast(unsigned, f);
    unsigned r = (u + 0x7fffu + ((u >> 16) & 1u)) >> 16;
    return (unsigned short)r;
}

__device__ __forceinline__ float bf2f(unsigned short u) {
    return __builtin_bit_cast(float, (unsigned)u << 16);
}

// ---------------- feature transform via MFMA, logits as augmented GEMM columns ----------------
__global__ __launch_bounds__(256) void k_linm(
    const float* __restrict__ x0, const float* __restrict__ W0, const float* __restrict__ b0,
    const float* __restrict__ A00, const float* __restrict__ A01, const float* __restrict__ A02,
    unsigned short* __restrict__ h0,
    float* __restrict__ a00, float* __restrict__ a01, float* __restrict__ a02, int N0, int natt0,
    const float* __restrict__ x1, const float* __restrict__ W1, const float* __restrict__ b1,
    const float* __restrict__ A10, const float* __restrict__ A11, const float* __restrict__ A12,
    unsigned short* __restrict__ h1,
    float* __restrict__ a10, float* __restrict__ a11, float* __restrict__ a12, int N1, int natt1)
{
    const int y = blockIdx.y;
    const float* __restrict__ x  = y ? x1 : x0;
    const float* __restrict__ W  = y ? W1 : W0;
    const float* __restrict__ b  = y ? b1 : b0;
    const float* __restrict__ at0 = y ? A10 : A00;
    const float* __restrict__ at1 = y ? A11 : A01;
    const float* __restrict__ at2 = y ? A12 : A02;
    unsigned short* __restrict__ hb = y ? h1 : h0;
    float* __restrict__ a0 = y ? a10 : a00;
    float* __restrict__ a1 = y ? a11 : a01;
    float* __restrict__ a2 = y ? a12 : a02;
    const int N = y ? N1 : N0;
    const int natt = y ? natt1 : natt0;

    __shared__ unsigned short wtl[NCOL * DIN];  // W^T bf16, chunk-XOR swizzled (20 KB)
    __shared__ float attl[3][FOUT];
    __shared__ float bl[FOUT];
    __shared__ float abias[32];
    const int tid = threadIdx.x;

    if (tid < FOUT) {
        bl[tid] = b[tid];
        attl[0][tid] = at0[tid];
        attl[1][tid] = at1[tid];
        attl[2][tid] = at2[tid];
    }
    __syncthreads();

    for (int idx = tid; idx < DIN * FOUT; idx += 256) {
        int fi = idx >> 7, fo = idx & 127;
        wtl[fo * DIN + (((fi >> 3) ^ (fo & 7)) << 3) + (fi & 7)] = f2bf(W[idx]);
    }
    for (int idx = tid; idx < 2048; idx += 256) {
        int fi = idx >> 5, cs = idx & 31;
        float acc = 0.f;
        if (cs < 24) {
            int a = cs >> 3, hd = cs & 7;
            #pragma unroll
            for (int d = 0; d < 16; d++)
                acc += W[fi * FOUT + hd * 16 + d] * attl[a][hd * 16 + d];
        }
        int fo = 128 + cs;
        wtl[fo * DIN + (((fi >> 3) ^ (fo & 7)) << 3) + (fi & 7)] =
            cs < 24 ? f2bf(acc) : (unsigned short)0;
    }
    if (tid < 32) {
        float acc = 0.f;
        if (tid < 24) {
            int a = tid >> 3, hd = tid & 7;
            #pragma unroll
            for (int d = 0; d < 16; d++) acc += b[hd * 16 + d] * attl[a][hd * 16 + d];
        }
        abias[tid] = acc;
    }
    __syncthreads();

    const int w = tid >> 6, lane = tid & 63;
    const int rt = blockIdx.x * 4 + w;
    if (rt * 16 >= N) return;
    const int r16 = lane & 15, g = lane >> 4;

    int node = rt * 16 + r16;
    if (node >= N) node = N - 1;
    const float* xr = x + (size_t)node * DIN;
    bf16x8 af[2];
    #pragma unroll
    for (int kk = 0; kk < 2; kk++) {
        float4 v0 = *(const float4*)(xr + kk * 32 + g * 8);
        float4 v1 = *(const float4*)(xr + kk * 32 + g * 8 + 4);
        bf16x8 f;
        f[0] = (short)f2bf(v0.x); f[1] = (short)f2bf(v0.y);
        f[2] = (short)f2bf(v0.z); f[3] = (short)f2bf(v0.w);
        f[4] = (short)f2bf(v1.x); f[5] = (short)f2bf(v1.y);
        f[6] = (short)f2bf(v1.z); f[7] = (short)f2bf(v1.w);
        af[kk] = f;
    }

    #pragma unroll
    for (int j = 0; j < 10; j++) {
        const int fo = j * 16 + r16;
        f32x4 acc = {0.f, 0.f, 0.f, 0.f};
        #pragma unroll
        for (int kk = 0; kk < 2; kk++) {
            int c = (kk * 4 + g) ^ (fo & 7);
            bf16x8 bfr = *(bf16x8*)&wtl[fo * DIN + c * 8];
            acc = __builtin_amdgcn_mfma_f32_16x16x32_bf16(af[kk], bfr, acc, 0, 0, 0);
        }
        if (j < 8) {
            float bv = bl[fo];
            #pragma unroll
            for (int r = 0; r < 4; r++) {
                int nr = rt * 16 + g * 4 + r;
                if (nr < N) hb[(size_t)nr * FOUT + fo] = f2bf(acc[r] + bv);
            }
        } else {
            int cs = (j - 8) * 16 + r16;
            if (cs < 24) {
                int a = cs >> 3;
                if (a < natt) {
                    float* __restrict__ ga = a == 0 ? a0 : (a == 1 ? a1 : a2);
                    int hd = cs & 7;
                    float ab = abias[cs];
                    #pragma unroll
                    for (int r = 0; r < 4; r++) {
                        int nr = rt * 16 + g * 4 + r;
                        if (nr < N) ga[(size_t)nr * HH + hd] = acc[r] + ab;
                    }
                }
            }
        }
    }
}

// ---------------- CSR pass 1: per-(type,bin,chunk) histogram, dense store, NO global atomics ----
// Grid mapping bx = chunk*nbp + tb (nbp%8==0) pins each (type,bin) to one XCD.
__global__ __launch_bounds__(256) void k_hist(
    const int* __restrict__ e0, int E0, const int* __restrict__ e1, int E1,
    int* __restrict__ chist, int nbin, int nbp)
{
    const int bx = blockIdx.x;
    const int chunk = bx / nbp;
    const int tb = bx % nbp;
    if (tb >= 2 * nbin) return;
    const bool type = tb >= nbin;
    const int bin = type ? tb - nbin : tb;
    const int* __restrict__ e = type ? e1 : e0;
    const int E = type ? E1 : E0;
    const int lo = bin * HR;

    __shared__ int hist[HR];
    for (int j = threadIdx.x; j < HR; j += 256) hist[j] = 0;
    __syncthreads();

    const int per = (E + CHUNKN - 1) / CHUNKN;
    const int s0 = chunk * per;
    const int s1 = s0 + per < E ? s0 + per : E;
    for (int i = s0 + threadIdx.x; i < s1; i += 256) {
        unsigned r = (unsigned)(e[E + i] - lo);
        if (r < HR) atomicAdd(&hist[r], 1);   // LDS atomic only
    }
    __syncthreads();
    int* __restrict__ out = chist + ((size_t)tb * CHUNKN + chunk) * HR;
    for (int j = threadIdx.x; j < HR; j += 256) out[j] = hist[j];
}

// ---------------- CSR pass 2: deg from chunk-hists, block scan, per-chunk exclusive offsets ----
__global__ __launch_bounds__(256) void k_scan_block2(
    int* __restrict__ chist,
    int* __restrict__ out0, int* __restrict__ bs0,
    int* __restrict__ out1, int* __restrict__ bs1,
    int* __restrict__ d0, int* __restrict__ d1,
    int n, int nbin)
{
    const int type = blockIdx.y;
    int* __restrict__ out = type ? out1 : out0;
    int* __restrict__ bsum = type ? bs1 : bs0;
    int* __restrict__ deg = type ? d1 : d0;
    __shared__ int s[256];
    const int tid = threadIdx.x;
    const int i = blockIdx.x * 256 + tid;
    int v = 0;
    int hvals[CHUNKN];
    int* hp = nullptr;
    if (i < n) {
        const int bin = i / HR, jr = i & (HR - 1);
        hp = chist + ((size_t)(type * nbin + bin) * CHUNKN) * HR + jr;
        #pragma unroll
        for (int c = 0; c < CHUNKN; c++) { hvals[c] = hp[c * HR]; v += hvals[c]; }
    }
    s[tid] = v; __syncthreads();
    for (int off = 1; off < 256; off <<= 1) {
        int t = tid >= off ? s[tid - off] : 0;
        __syncthreads();
        s[tid] += t;
        __syncthreads();
    }
    if (i < n) {
        out[i] = s[tid] - v;          // exclusive rowptr (bsum added later)
        deg[i] = v;
        int run = 0;                  // exclusive prefix over chunks -> choff
        #pragma unroll
        for (int c = 0; c < CHUNKN; c++) { int t = hvals[c]; hp[c * HR] = run; run += t; }
    }
    if (tid == 255) bsum[blockIdx.x] = s[255];
}

__global__ __launch_bounds__(512) void k_scan_partial2(int* __restrict__ b0, int* __restrict__ b1, int nb) {
    int* bs = blockIdx.x ? b1 : b0;
    __shared__ int s[512];
    const int tid = threadIdx.x;
    int v = tid < nb ? bs[tid] : 0;
    s[tid] = v; __syncthreads();
    for (int off = 1; off < 512; off <<= 1) {
        int t = tid >= off ? s[tid - off] : 0;
        __syncthreads();
        s[tid] += t;
        __syncthreads();
    }
    if (tid < nb) bs[tid] = s[tid] - v;
}

__global__ __launch_bounds__(256) void k_scan_add2(
    int* __restrict__ o0, const int* __restrict__ b0,
    int* __restrict__ o1, const int* __restrict__ b1, int n)
{
    int* out = blockIdx.y ? o1 : o0;
    const int* bsum = blockIdx.y ? b1 : b0;
    int i = blockIdx.x * 256 + threadIdx.x;
    if (i < n) out[i] += bsum[blockIdx.x];
}

// ---------------- CSR pass 3: scatter; cnt initialized to choff so atomicAdd yields position ----
__global__ __launch_bounds__(256) void k_scatb(
    const int* __restrict__ e0, int E0, const int* __restrict__ rp0, int* __restrict__ sl0,
    const int* __restrict__ e1, int E1, const int* __restrict__ rp1, int* __restrict__ sl1,
    const int* __restrict__ chist, int nbin, int nbp)
{
    const int bx = blockIdx.x;
    const int chunk = bx / nbp;
    const int tb = bx % nbp;
    if (tb >= 2 * nbin) return;
    const bool type = tb >= nbin;
    const int bin = type ? tb - nbin : tb;
    const int* __restrict__ e = type ? e1 : e0;
    const int E = type ? E1 : E0;
    const int* __restrict__ rp = type ? rp1 : rp0;
    int* __restrict__ sl = type ? sl1 : sl0;
    const int lo = bin * HR;

    __shared__ int cnt[HR];   // 16 KB only: starts at choff, atomicAdd returns choff+rank
    const int* __restrict__ cop = chist + ((size_t)tb * CHUNKN + chunk) * HR;
    for (int j = threadIdx.x; j < HR; j += 256) cnt[j] = cop[j];
    __syncthreads();

    const int per = (E + CHUNKN - 1) / CHUNKN;
    const int s0 = chunk * per;
    const int s1 = s0 + per < E ? s0 + per : E;
    for (int i = s0 + threadIdx.x; i < s1; i += 256) {
        int dst = e[E + i];
        unsigned r = (unsigned)(dst - lo);
        if (r < HR) {
            int pos = rp[dst] + atomicAdd(&cnt[r], 1);   // LDS atomic only
            sl[pos] = e[i];
        }
    }
}

// ---------------- aggregation: 32 lanes per dst, bf16 gathers, bf16 o output ----------------
__global__ __launch_bounds__(256) void k_agg2(
    const int* __restrict__ sl0, const int* __restrict__ rp0, const int* __restrict__ dg0,
    const unsigned short* __restrict__ xb0, const float* __restrict__ as0, const float* __restrict__ ad0,
    unsigned short* __restrict__ oo0,
    const int* __restrict__ sl1, const int* __restrict__ rp1, const int* __restrict__ dg1,
    const unsigned short* __restrict__ xb1, const float* __restrict__ as1, const float* __restrict__ ad1,
    unsigned short* __restrict__ oo1,
    int N)
{
    const bool m = blockIdx.y;
    const int* __restrict__ sl = m ? sl1 : sl0;
    const int* __restrict__ rp = m ? rp1 : rp0;
    const int* __restrict__ dg = m ? dg1 : dg0;
    const unsigned short* __restrict__ xb = m ? xb1 : xb0;
    const float* __restrict__ as_ = m ? as1 : as0;
    const float* __restrict__ ad_ = m ? ad1 : ad0;
    unsigned short* __restrict__ oo = m ? oo1 : oo0;

    const int t = blockIdx.x * 256 + threadIdx.x;
    const int dst = t >> 5;
    if (dst >= N) return;
    const int lane = t & 31;
    const int h = lane >> 2;
    const int d = dg[dst];
    const int base = rp[dst];
    const float adv = ad_[(size_t)dst * HH + h];
    float acc0 = 0.f, acc1 = 0.f, acc2 = 0.f, acc3 = 0.f;
    float wsum = 0.f;
    int src_next = d > 0 ? sl[base] : 0;
    for (int k = 0; k < d; k++) {
        int src = src_next;
        if (k + 1 < d) src_next = sl[base + k + 1];
        float a = as_[(size_t)src * HH + h] + adv;
        a = a > 0.f ? a : NSLOPE * a;
        float wv = __expf(a);
        uint2 xv = *(const uint2*)(xb + (size_t)src * FOUT + lane * 4);
        acc0 = fmaf(wv, bf2f((unsigned short)(xv.x & 0xffff)), acc0);
        acc1 = fmaf(wv, bf2f((unsigned short)(xv.x >> 16)), acc1);
        acc2 = fmaf(wv, bf2f((unsigned short)(xv.y & 0xffff)), acc2);
        acc3 = fmaf(wv, bf2f((unsigned short)(xv.y >> 16)), acc3);
        wsum += wv;
    }
    float inv = fast_rcp(wsum + 1e-16f);
    unsigned p0 = ((unsigned)f2bf(fmaxf(acc1 * inv, 0.f)) << 16) | f2bf(fmaxf(acc0 * inv, 0.f));
    unsigned p1 = ((unsigned)f2bf(fmaxf(acc3 * inv, 0.f)) << 16) | f2bf(fmaxf(acc2 * inv, 0.f));
    *(uint2*)(oo + (size_t)dst * FOUT + lane * 4) = make_uint2(p0, p1);
}

// ---------------- semantic score: bf16 MFMA GEMM + tanh·q reduce (o already bf16) ----------------
__global__ __launch_bounds__(256) void k_sem(
    const unsigned short* __restrict__ o1, const unsigned short* __restrict__ o2,
    const float* __restrict__ kw, const float* __restrict__ kb,
    const float* __restrict__ q, float* __restrict__ score, int N)
{
    __shared__ unsigned short kwl[FOUT * FOUT];  // kw^T bf16, chunk-XOR swizzled
    __shared__ float red[256];
    const int tid = threadIdx.x;
    const int m = blockIdx.y;
    const unsigned short* o = m ? o2 : o1;

    for (int idx = tid; idx < FOUT * FOUT; idx += 256) {
        int fi = idx >> 7, fo = idx & 127;
        int c = (fi >> 3) ^ (fo & 15);
        kwl[fo * 128 + c * 8 + (fi & 7)] = f2bf(kw[idx]);
    }
    __syncthreads();

    const int lane = tid & 63;
    const int w = tid >> 6;
    const int n0 = blockIdx.x * 256 + w * 64;
    const int r16 = lane & 15;
    const int g = lane >> 4;

    float qv[8], kbv[8];
    #pragma unroll
    for (int j = 0; j < 8; j++) { qv[j] = q[j * 16 + r16]; kbv[j] = kb[j * 16 + r16]; }

    bf16x8 afrag[4][4];
    #pragma unroll
    for (int i = 0; i < 4; i++) {
        int node = n0 + i * 16 + r16;
        if (node > N - 1) node = N - 1;
        const unsigned short* rowp = o + (size_t)node * FOUT + g * 8;
        #pragma unroll
        for (int kk = 0; kk < 4; kk++)
            afrag[i][kk] = *(const bf16x8*)(rowp + kk * 32);
    }

    float part = 0.f;
    #pragma unroll
    for (int j = 0; j < 8; j++) {
        const int fo = j * 16 + r16;
        f32x4 acc0 = {0.f,0.f,0.f,0.f}, acc1 = {0.f,0.f,0.f,0.f};
        f32x4 acc2 = {0.f,0.f,0.f,0.f}, acc3 = {0.f,0.f,0.f,0.f};
        #pragma unroll
        for (int kk = 0; kk < 4; kk++) {
            int c = (kk * 4 + g) ^ (fo & 15);
            bf16x8 bfr = *(bf16x8*)&kwl[fo * 128 + c * 8];
            acc0 = __builtin_amdgcn_mfma_f32_16x16x32_bf16(afrag[0][kk], bfr, acc0, 0, 0, 0);
            acc1 = __builtin_amdgcn_mfma_f32_16x16x32_bf16(afrag[1][kk], bfr, acc1, 0, 0, 0);
            acc2 = __builtin_amdgcn_mfma_f32_16x16x32_bf16(afrag[2][kk], bfr, acc2, 0, 0, 0);
            acc3 = __builtin_amdgcn_mfma_f32_16x16x32_bf16(afrag[3][kk], bfr, acc3, 0, 0, 0);
        }
        #pragma unroll
        for (int i = 0; i < 4; i++) {
            f32x4 a = i == 0 ? acc0 : (i == 1 ? acc1 : (i == 2 ? acc2 : acc3));
            #pragma unroll
            for (int r = 0; r < 4; r++) {
                int node = n0 + i * 16 + g * 4 + r;
                if (node < N) part += fast_tanh(a[r] + kbv[j]) * qv[j];
            }
        }
    }
    red[tid] = part;
    __syncthreads();
    for (int s2 = 128; s2 > 0; s2 >>= 1) {
        if (tid < s2) red[tid] += red[tid + s2];
        __syncthreads();
    }
    if (tid == 0) atomicAdd(score + m, red[0]);
}

// ---------------- final: per-block softmax of the 2 scores ----------------
__global__ __launch_bounds__(256) void k_final(
    const unsigned short* __restrict__ o1, const unsigned short* __restrict__ o2,
    const float* __restrict__ score, float invN,
    const float* __restrict__ lw, const float* __restrict__ lb,
    float* __restrict__ out, int N)
{
    __shared__ float lwl[FOUT * 2];
    __shared__ float attns[2];
    const int tid = threadIdx.x;
    if (tid < FOUT * 2) lwl[tid] = lw[tid];
    if (tid == 0) {
        float s0 = score[0] * invN, s1 = score[1] * invN;
        float mm = fmaxf(s0, s1);
        float e0 = __expf(s0 - mm), e1 = __expf(s1 - mm);
        float inv = 1.f / (e0 + e1);
        attns[0] = e0 * inv;
        attns[1] = e1 * inv;
    }
    __syncthreads();
    const int n = blockIdx.x * 256 + tid;
    if (n >= N) return;
    const float a0 = attns[0], a1 = attns[1];
    float acc0 = lb[0], acc1 = lb[1];
    const uint4* p1 = (const uint4*)(o1 + (size_t)n * FOUT);
    const uint4* p2 = (const uint4*)(o2 + (size_t)n * FOUT);
    #pragma unroll
    for (int i = 0; i < FOUT / 8; i++) {   // 8 bf16 per uint4
        uint4 v1 = p1[i];
        uint4 v2 = p2[i];
        const unsigned w1[4] = {v1.x, v1.y, v1.z, v1.w};
        const unsigned w2[4] = {v2.x, v2.y, v2.z, v2.w};
        #pragma unroll
        for (int c = 0; c < 4; c++) {
            int f = i * 8 + c * 2;
            float f0 = a0 * bf2f((unsigned short)(w1[c] & 0xffff)) +
                       a1 * bf2f((unsigned short)(w2[c] & 0xffff));
            float f1 = a0 * bf2f((unsigned short)(w1[c] >> 16)) +
                       a1 * bf2f((unsigned short)(w2[c] >> 16));
            acc0 += f0 * lwl[f*2]   + f1 * lwl[(f+1)*2];
            acc1 += f0 * lwl[f*2+1] + f1 * lwl[(f+1)*2+1];
        }
    }
    *(float2*)(out + (size_t)n * 2) = make_float2(acc0, acc1);
}

extern "C" void kernel_launch(void* const* d_in, const int* in_sizes, int n_in,
                              void* d_out, int out_size, void* d_ws, size_t ws_size,
                              hipStream_t stream)
{
    const float* x_subj = (const float*)d_in[0];
    const float* x_chan = (const float*)d_in[1];
    const int*   e_cs   = (const int*)d_in[2];
    const int*   e_ss   = (const int*)d_in[3];
    const float* W_s    = (const float*)d_in[4];
    const float* b_s    = (const float*)d_in[5];
    const float* W_c    = (const float*)d_in[6];
    const float* b_c    = (const float*)d_in[7];
    const float* att_src_cs = (const float*)d_in[8];
    const float* att_dst_cs = (const float*)d_in[9];
    const float* att_src_ss = (const float*)d_in[10];
    const float* att_dst_ss = (const float*)d_in[11];
    const float* k_w  = (const float*)d_in[12];
    const float* k_b  = (const float*)d_in[13];
    const float* q    = (const float*)d_in[14];
    const float* lw   = (const float*)d_in[15];
    const float* lb   = (const float*)d_in[16];

    const int Ns  = in_sizes[0] / DIN;
    const int Nc  = in_sizes[1] / DIN;
    const int Ecs = in_sizes[2] / 2;
    const int Ess = in_sizes[3] / 2;

    const int nbin = (Ns + HR - 1) / HR;
    const int nbp = ((2 * nbin + 7) / 8) * 8;   // pad (type,bin) space to mult of 8 -> XCD pin

    // ---- workspace layout (all chunks 16B-aligned) ----
    char* p = (char*)d_ws;
    unsigned short* hbf_s = (unsigned short*)p; p += (size_t)Ns * FOUT * 2;
    unsigned short* hbf_c = (unsigned short*)p; p += (size_t)Nc * FOUT * 2;
    float* a_src_cs_ = (float*)p; p += (size_t)Nc * HH * 4;
    float* a_dst_cs_ = (float*)p; p += (size_t)Ns * HH * 4;
    float* a_src_ss_ = (float*)p; p += (size_t)Ns * HH * 4;
    float* a_dst_ss_ = (float*)p; p += (size_t)Ns * HH * 4;
    unsigned short* o1 = (unsigned short*)p; p += (size_t)Ns * FOUT * 2;
    unsigned short* o2 = (unsigned short*)p; p += (size_t)Ns * FOUT * 2;
    int* srclist_cs  = (int*)p;   p += (size_t)Ecs * 4;
    int* srclist_ss  = (int*)p;   p += (size_t)Ess * 4;
    int* rowptr_cs   = (int*)p;   p += (size_t)Ns * 4;
    int* rowptr_ss   = (int*)p;   p += (size_t)Ns * 4;
    int* deg_cs      = (int*)p;   p += (size_t)Ns * 4;
    int* deg_ss      = (int*)p;   p += (size_t)Ns * 4;
    int* bsum0       = (int*)p;   p += 2048;
    int* bsum1       = (int*)p;   p += 2048;
    int* chist       = (int*)p;   p += (size_t)2 * nbin * CHUNKN * HR * 4;  // 6.5 MB
    // zeroed region: score only
    float* score = (float*)p; p += 16;   // [s0, s1]
    hipMemsetAsync(score, 0, 16, stream);

    const int nbN = (Ns + 255) / 256;
    const int Nmax = Ns > Nc ? Ns : Nc;
    const int gx_lin = ((Nmax + 15) / 16 + 3) / 4;

    // feature transforms + logits (both node types), one dispatch
    k_linm<<<dim3(gx_lin, 2), dim3(256), 0, stream>>>(
        x_subj, W_s, b_s, att_dst_cs, att_src_ss, att_dst_ss,
        hbf_s, a_dst_cs_, a_src_ss_, a_dst_ss_, Ns, 3,
        x_chan, W_c, b_c, att_src_cs, att_src_cs, att_src_cs,
        hbf_c, a_src_cs_, a_src_cs_, a_src_cs_, Nc, 1);

    // CSR build, atomic-free (per-chunk histograms + LDS rank scatter), XCD-pinned bins
    k_hist<<<dim3(nbp * CHUNKN), dim3(256), 0, stream>>>(
        e_cs, Ecs, e_ss, Ess, chist, nbin, nbp);
    k_scan_block2<<<dim3(nbN, 2), dim3(256), 0, stream>>>(
        chist, rowptr_cs, bsum0, rowptr_ss, bsum1, deg_cs, deg_ss, Ns, nbin);
    k_scan_partial2<<<dim3(2), dim3(512), 0, stream>>>(bsum0, bsum1, nbN);
    k_scan_add2<<<dim3(nbN, 2), dim3(256), 0, stream>>>(rowptr_cs, bsum0, rowptr_ss, bsum1, Ns);
    k_scatb<<<dim3(nbp * CHUNKN), dim3(256), 0, stream>>>(
        e_cs, Ecs, rowptr_cs, srclist_cs,
        e_ss, Ess, rowptr_ss, srclist_ss, chist, nbin, nbp);

    // aggregation (fused softmax-normalize + relu), both metapaths
    k_agg2<<<dim3(((size_t)Ns * 32 + 255) / 256, 2), dim3(256), 0, stream>>>(
        srclist_cs, rowptr_cs, deg_cs, hbf_c, a_src_cs_, a_dst_cs_, o1,
        srclist_ss, rowptr_ss, deg_ss, hbf_s, a_src_ss_, a_dst_ss_, o2, Ns);

    // semantic attention + fuse + output
    k_sem<<<dim3(nbN, 2), dim3(256), 0, stream>>>(o1, o2, k_w, k_b, q, score, Ns);
    k_final<<<dim3(nbN), dim3(256), 0, stream>>>(
        o1, o2, score, 1.f / (float)Ns, lw, lb, (float*)d_out, Ns);
}

// Round 9
// 271.858 us; speedup vs baseline: 1.4221x; 1.4221x over previous
//
#include <hip/hip_runtime.h>

#define HH 8
#define FOUT 128
#define DIN 64
#define NCOL 160          // 128 h cols + 24 logit cols + 8 pad (10 MFMA j-tiles)
#define NSLOPE 0.2f
#define HR 4096           // dst-range per CSR bin (16 KB LDS histogram)
#define CHUNKN 20         // edge-slice chunks per bin

typedef __attribute__((ext_vector_type(8))) short bf16x8;
typedef __attribute__((ext_vector_type(4))) float f32x4;

__device__ __forceinline__ float fast_rcp(float x) { return __builtin_amdgcn_rcpf(x); }

__device__ __forceinline__ float fast_tanh(float x) {
    float ax = fabsf(x);
    float e = __expf(-2.f * ax);
    float r = (1.f - e) * fast_rcp(1.f + e);
    return x >= 0.f ? r : -r;
}

__device__ __forceinline__ unsigned short f2bf(float f) {
    unsigned u = __builtin_bit_cast(unsigned, f);
    unsigned r = (u + 0x7fffu + ((u >> 16) & 1u)) >> 16;
    return (unsigned short)r;
}

__device__ __forceinline__ float bf2f(unsigned short u) {
    return __builtin_bit_cast(float, (unsigned)u << 16);
}

// ---------------- feature transform via MFMA, logits as augmented GEMM columns ----------------
__global__ __launch_bounds__(256) void k_linm(
    const float* __restrict__ x0, const float* __restrict__ W0, const float* __restrict__ b0,
    const float* __restrict__ A00, const float* __restrict__ A01, const float* __restrict__ A02,
    unsigned short* __restrict__ h0,
    float* __restrict__ a00, float* __restrict__ a01, float* __restrict__ a02, int N0, int natt0,
    const float* __restrict__ x1, const float* __restrict__ W1, const float* __restrict__ b1,
    const float* __restrict__ A10, const float* __restrict__ A11, const float* __restrict__ A12,
    unsigned short* __restrict__ h1,
    float* __restrict__ a10, float* __restrict__ a11, float* __restrict__ a12, int N1, int natt1)
{
    const int y = blockIdx.y;
    const float* __restrict__ x  = y ? x1 : x0;
    const float* __restrict__ W  = y ? W1 : W0;
    const float* __restrict__ b  = y ? b1 : b0;
    const float* __restrict__ at0 = y ? A10 : A00;
    const float* __restrict__ at1 = y ? A11 : A01;
    const float* __restrict__ at2 = y ? A12 : A02;
    unsigned short* __restrict__ hb = y ? h1 : h0;
    float* __restrict__ a0 = y ? a10 : a00;
    float* __restrict__ a1 = y ? a11 : a01;
    float* __restrict__ a2 = y ? a12 : a02;
    const int N = y ? N1 : N0;
    const int natt = y ? natt1 : natt0;

    __shared__ unsigned short wtl[NCOL * DIN];  // W^T bf16, chunk-XOR swizzled (20 KB)
    __shared__ float attl[3][FOUT];
    __shared__ float bl[FOUT];
    __shared__ float abias[32];
    const int tid = threadIdx.x;

    if (tid < FOUT) {
        bl[tid] = b[tid];
        attl[0][tid] = at0[tid];
        attl[1][tid] = at1[tid];
        attl[2][tid] = at2[tid];
    }
    __syncthreads();

    for (int idx = tid; idx < DIN * FOUT; idx += 256) {
        int fi = idx >> 7, fo = idx & 127;
        wtl[fo * DIN + (((fi >> 3) ^ (fo & 7)) << 3) + (fi & 7)] = f2bf(W[idx]);
    }
    for (int idx = tid; idx < 2048; idx += 256) {
        int fi = idx >> 5, cs = idx & 31;
        float acc = 0.f;
        if (cs < 24) {
            int a = cs >> 3, hd = cs & 7;
            #pragma unroll
            for (int d = 0; d < 16; d++)
                acc += W[fi * FOUT + hd * 16 + d] * attl[a][hd * 16 + d];
        }
        int fo = 128 + cs;
        wtl[fo * DIN + (((fi >> 3) ^ (fo & 7)) << 3) + (fi & 7)] =
            cs < 24 ? f2bf(acc) : (unsigned short)0;
    }
    if (tid < 32) {
        float acc = 0.f;
        if (tid < 24) {
            int a = tid >> 3, hd = tid & 7;
            #pragma unroll
            for (int d = 0; d < 16; d++) acc += b[hd * 16 + d] * attl[a][hd * 16 + d];
        }
        abias[tid] = acc;
    }
    __syncthreads();

    const int w = tid >> 6, lane = tid & 63;
    const int rt = blockIdx.x * 4 + w;
    if (rt * 16 >= N) return;
    const int r16 = lane & 15, g = lane >> 4;

    int node = rt * 16 + r16;
    if (node >= N) node = N - 1;
    const float* xr = x + (size_t)node * DIN;
    bf16x8 af[2];
    #pragma unroll
    for (int kk = 0; kk < 2; kk++) {
        float4 v0 = *(const float4*)(xr + kk * 32 + g * 8);
        float4 v1 = *(const float4*)(xr + kk * 32 + g * 8 + 4);
        bf16x8 f;
        f[0] = (short)f2bf(v0.x); f[1] = (short)f2bf(v0.y);
        f[2] = (short)f2bf(v0.z); f[3] = (short)f2bf(v0.w);
        f[4] = (short)f2bf(v1.x); f[5] = (short)f2bf(v1.y);
        f[6] = (short)f2bf(v1.z); f[7] = (short)f2bf(v1.w);
        af[kk] = f;
    }

    #pragma unroll
    for (int j = 0; j < 10; j++) {
        const int fo = j * 16 + r16;
        f32x4 acc = {0.f, 0.f, 0.f, 0.f};
        #pragma unroll
        for (int kk = 0; kk < 2; kk++) {
            int c = (kk * 4 + g) ^ (fo & 7);
            bf16x8 bfr = *(bf16x8*)&wtl[fo * DIN + c * 8];
            acc = __builtin_amdgcn_mfma_f32_16x16x32_bf16(af[kk], bfr, acc, 0, 0, 0);
        }
        if (j < 8) {
            float bv = bl[fo];
            #pragma unroll
            for (int r = 0; r < 4; r++) {
                int nr = rt * 16 + g * 4 + r;
                if (nr < N) hb[(size_t)nr * FOUT + fo] = f2bf(acc[r] + bv);
            }
        } else {
            int cs = (j - 8) * 16 + r16;
            if (cs < 24) {
                int a = cs >> 3;
                if (a < natt) {
                    float* __restrict__ ga = a == 0 ? a0 : (a == 1 ? a1 : a2);
                    int hd = cs & 7;
                    float ab = abias[cs];
                    #pragma unroll
                    for (int r = 0; r < 4; r++) {
                        int nr = rt * 16 + g * 4 + r;
                        if (nr < N) ga[(size_t)nr * HH + hd] = acc[r] + ab;
                    }
                }
            }
        }
    }
}

// ---------------- CSR pass 1: per-(type,bin,chunk) histogram, dense store, NO global atomics ----
// Grid mapping bx = chunk*nbp + tb (nbp%8==0) pins each (type,bin) to one XCD.
// 512 threads/block: the kernel is a latency-bound streaming scan -> needs wave count.
__global__ __launch_bounds__(512) void k_hist(
    const int* __restrict__ e0, int E0, const int* __restrict__ e1, int E1,
    int* __restrict__ chist, int nbin, int nbp)
{
    const int bx = blockIdx.x;
    const int chunk = bx / nbp;
    const int tb = bx % nbp;
    if (tb >= 2 * nbin) return;
    const bool type = tb >= nbin;
    const int bin = type ? tb - nbin : tb;
    const int* __restrict__ e = type ? e1 : e0;
    const int E = type ? E1 : E0;
    const int lo = bin * HR;

    __shared__ int hist[HR];
    for (int j = threadIdx.x; j < HR; j += 512) hist[j] = 0;
    __syncthreads();

    const int per = (E + CHUNKN - 1) / CHUNKN;
    const int s0 = chunk * per;
    const int s1 = s0 + per < E ? s0 + per : E;
    for (int i = s0 + threadIdx.x; i < s1; i += 512) {
        unsigned r = (unsigned)(e[E + i] - lo);
        if (r < HR) atomicAdd(&hist[r], 1);   // LDS atomic only
    }
    __syncthreads();
    int* __restrict__ out = chist + ((size_t)tb * CHUNKN + chunk) * HR;
    for (int j = threadIdx.x; j < HR; j += 512) out[j] = hist[j];
}

// ---------------- CSR pass 2: deg from chunk-hists, block scan, per-chunk exclusive offsets ----
__global__ __launch_bounds__(256) void k_scan_block2(
    int* __restrict__ chist,
    int* __restrict__ out0, int* __restrict__ bs0,
    int* __restrict__ out1, int* __restrict__ bs1,
    int* __restrict__ d0, int* __restrict__ d1,
    int n, int nbin)
{
    const int type = blockIdx.y;
    int* __restrict__ out = type ? out1 : out0;
    int* __restrict__ bsum = type ? bs1 : bs0;
    int* __restrict__ deg = type ? d1 : d0;
    __shared__ int s[256];
    const int tid = threadIdx.x;
    const int i = blockIdx.x * 256 + tid;
    int v = 0;
    int hvals[CHUNKN];
    int* hp = nullptr;
    if (i < n) {
        const int bin = i / HR, jr = i & (HR - 1);
        hp = chist + ((size_t)(type * nbin + bin) * CHUNKN) * HR + jr;
        #pragma unroll
        for (int c = 0; c < CHUNKN; c++) { hvals[c] = hp[c * HR]; v += hvals[c]; }
    }
    s[tid] = v; __syncthreads();
    for (int off = 1; off < 256; off <<= 1) {
        int t = tid >= off ? s[tid - off] : 0;
        __syncthreads();
        s[tid] += t;
        __syncthreads();
    }
    if (i < n) {
        out[i] = s[tid] - v;          // exclusive rowptr (bsum added later)
        deg[i] = v;
        int run = 0;                  // exclusive prefix over chunks -> choff
        #pragma unroll
        for (int c = 0; c < CHUNKN; c++) { int t = hvals[c]; hp[c * HR] = run; run += t; }
    }
    if (tid == 255) bsum[blockIdx.x] = s[255];
}

__global__ __launch_bounds__(512) void k_scan_partial2(int* __restrict__ b0, int* __restrict__ b1, int nb) {
    int* bs = blockIdx.x ? b1 : b0;
    __shared__ int s[512];
    const int tid = threadIdx.x;
    int v = tid < nb ? bs[tid] : 0;
    s[tid] = v; __syncthreads();
    for (int off = 1; off < 512; off <<= 1) {
        int t = tid >= off ? s[tid - off] : 0;
        __syncthreads();
        s[tid] += t;
        __syncthreads();
    }
    if (tid < nb) bs[tid] = s[tid] - v;
}

__global__ __launch_bounds__(256) void k_scan_add2(
    int* __restrict__ o0, const int* __restrict__ b0,
    int* __restrict__ o1, const int* __restrict__ b1, int n)
{
    int* out = blockIdx.y ? o1 : o0;
    const int* bsum = blockIdx.y ? b1 : b0;
    int i = blockIdx.x * 256 + threadIdx.x;
    if (i < n) out[i] += bsum[blockIdx.x];
}

// ---------------- CSR pass 3: scatter; cnt initialized to choff so atomicAdd yields position ----
__global__ __launch_bounds__(512) void k_scatb(
    const int* __restrict__ e0, int E0, const int* __restrict__ rp0, int* __restrict__ sl0,
    const int* __restrict__ e1, int E1, const int* __restrict__ rp1, int* __restrict__ sl1,
    const int* __restrict__ chist, int nbin, int nbp)
{
    const int bx = blockIdx.x;
    const int chunk = bx / nbp;
    const int tb = bx % nbp;
    if (tb >= 2 * nbin) return;
    const bool type = tb >= nbin;
    const int bin = type ? tb - nbin : tb;
    const int* __restrict__ e = type ? e1 : e0;
    const int E = type ? E1 : E0;
    const int* __restrict__ rp = type ? rp1 : rp0;
    int* __restrict__ sl = type ? sl1 : sl0;
    const int lo = bin * HR;

    __shared__ int cnt[HR];   // 16 KB: starts at choff, atomicAdd returns choff+rank
    const int* __restrict__ cop = chist + ((size_t)tb * CHUNKN + chunk) * HR;
    for (int j = threadIdx.x; j < HR; j += 512) cnt[j] = cop[j];
    __syncthreads();

    const int per = (E + CHUNKN - 1) / CHUNKN;
    const int s0 = chunk * per;
    const int s1 = s0 + per < E ? s0 + per : E;
    for (int i = s0 + threadIdx.x; i < s1; i += 512) {
        int dst = e[E + i];
        unsigned r = (unsigned)(dst - lo);
        if (r < HR) {
            int pos = rp[dst] + atomicAdd(&cnt[r], 1);   // LDS atomic only
            sl[pos] = e[i];
        }
    }
}

// ---------------- aggregation: 32 lanes per dst, bf16 gathers, bf16 o output ----------------
__global__ __launch_bounds__(256) void k_agg2(
    const int* __restrict__ sl0, const int* __restrict__ rp0, const int* __restrict__ dg0,
    const unsigned short* __restrict__ xb0, const float* __restrict__ as0, const float* __restrict__ ad0,
    unsigned short* __restrict__ oo0,
    const int* __restrict__ sl1, const int* __restrict__ rp1, const int* __restrict__ dg1,
    const unsigned short* __restrict__ xb1, const float* __restrict__ as1, const float* __restrict__ ad1,
    unsigned short* __restrict__ oo1,
    int N)
{
    const bool m = blockIdx.y;
    const int* __restrict__ sl = m ? sl1 : sl0;
    const int* __restrict__ rp = m ? rp1 : rp0;
    const int* __restrict__ dg = m ? dg1 : dg0;
    const unsigned short* __restrict__ xb = m ? xb1 : xb0;
    const float* __restrict__ as_ = m ? as1 : as0;
    const float* __restrict__ ad_ = m ? ad1 : ad0;
    unsigned short* __restrict__ oo = m ? oo1 : oo0;

    const int t = blockIdx.x * 256 + threadIdx.x;
    const int dst = t >> 5;
    if (dst >= N) return;
    const int lane = t & 31;
    const int h = lane >> 2;
    const int d = dg[dst];
    const int base = rp[dst];
    const float adv = ad_[(size_t)dst * HH + h];
    float acc0 = 0.f, acc1 = 0.f, acc2 = 0.f, acc3 = 0.f;
    float wsum = 0.f;
    int src_next = d > 0 ? sl[base] : 0;
    for (int k = 0; k < d; k++) {
        int src = src_next;
        if (k + 1 < d) src_next = sl[base + k + 1];
        float a = as_[(size_t)src * HH + h] + adv;
        a = a > 0.f ? a : NSLOPE * a;
        float wv = __expf(a);
        uint2 xv = *(const uint2*)(xb + (size_t)src * FOUT + lane * 4);
        acc0 = fmaf(wv, bf2f((unsigned short)(xv.x & 0xffff)), acc0);
        acc1 = fmaf(wv, bf2f((unsigned short)(xv.x >> 16)), acc1);
        acc2 = fmaf(wv, bf2f((unsigned short)(xv.y & 0xffff)), acc2);
        acc3 = fmaf(wv, bf2f((unsigned short)(xv.y >> 16)), acc3);
        wsum += wv;
    }
    float inv = fast_rcp(wsum + 1e-16f);
    unsigned p0 = ((unsigned)f2bf(fmaxf(acc1 * inv, 0.f)) << 16) | f2bf(fmaxf(acc0 * inv, 0.f));
    unsigned p1 = ((unsigned)f2bf(fmaxf(acc3 * inv, 0.f)) << 16) | f2bf(fmaxf(acc2 * inv, 0.f));
    *(uint2*)(oo + (size_t)dst * FOUT + lane * 4) = make_uint2(p0, p1);
}

// ---------------- semantic score: bf16 MFMA GEMM + tanh·q reduce (o already bf16) ----------------
__global__ __launch_bounds__(256) void k_sem(
    const unsigned short* __restrict__ o1, const unsigned short* __restrict__ o2,
    const float* __restrict__ kw, const float* __restrict__ kb,
    const float* __restrict__ q, float* __restrict__ score, int N)
{
    __shared__ unsigned short kwl[FOUT * FOUT];  // kw^T bf16, chunk-XOR swizzled
    __shared__ float red[256];
    const int tid = threadIdx.x;
    const int m = blockIdx.y;
    const unsigned short* o = m ? o2 : o1;

    for (int idx = tid; idx < FOUT * FOUT; idx += 256) {
        int fi = idx >> 7, fo = idx & 127;
        int c = (fi >> 3) ^ (fo & 15);
        kwl[fo * 128 + c * 8 + (fi & 7)] = f2bf(kw[idx]);
    }
    __syncthreads();

    const int lane = tid & 63;
    const int w = tid >> 6;
    const int n0 = blockIdx.x * 256 + w * 64;
    const int r16 = lane & 15;
    const int g = lane >> 4;

    float qv[8], kbv[8];
    #pragma unroll
    for (int j = 0; j < 8; j++) { qv[j] = q[j * 16 + r16]; kbv[j] = kb[j * 16 + r16]; }

    bf16x8 afrag[4][4];
    #pragma unroll
    for (int i = 0; i < 4; i++) {
        int node = n0 + i * 16 + r16;
        if (node > N - 1) node = N - 1;
        const unsigned short* rowp = o + (size_t)node * FOUT + g * 8;
        #pragma unroll
        for (int kk = 0; kk < 4; kk++)
            afrag[i][kk] = *(const bf16x8*)(rowp + kk * 32);
    }

    float part = 0.f;
    #pragma unroll
    for (int j = 0; j < 8; j++) {
        const int fo = j * 16 + r16;
        f32x4 acc0 = {0.f,0.f,0.f,0.f}, acc1 = {0.f,0.f,0.f,0.f};
        f32x4 acc2 = {0.f,0.f,0.f,0.f}, acc3 = {0.f,0.f,0.f,0.f};
        #pragma unroll
        for (int kk = 0; kk < 4; kk++) {
            int c = (kk * 4 + g) ^ (fo & 15);
            bf16x8 bfr = *(bf16x8*)&kwl[fo * 128 + c * 8];
            acc0 = __builtin_amdgcn_mfma_f32_16x16x32_bf16(afrag[0][kk], bfr, acc0, 0, 0, 0);
            acc1 = __builtin_amdgcn_mfma_f32_16x16x32_bf16(afrag[1][kk], bfr, acc1, 0, 0, 0);
            acc2 = __builtin_amdgcn_mfma_f32_16x16x32_bf16(afrag[2][kk], bfr, acc2, 0, 0, 0);
            acc3 = __builtin_amdgcn_mfma_f32_16x16x32_bf16(afrag[3][kk], bfr, acc3, 0, 0, 0);
        }
        #pragma unroll
        for (int i = 0; i < 4; i++) {
            f32x4 a = i == 0 ? acc0 : (i == 1 ? acc1 : (i == 2 ? acc2 : acc3));
            #pragma unroll
            for (int r = 0; r < 4; r++) {
                int node = n0 + i * 16 + g * 4 + r;
                if (node < N) part += fast_tanh(a[r] + kbv[j]) * qv[j];
            }
        }
    }
    red[tid] = part;
    __syncthreads();
    for (int s2 = 128; s2 > 0; s2 >>= 1) {
        if (tid < s2) red[tid] += red[tid + s2];
        __syncthreads();
    }
    if (tid == 0) atomicAdd(score + m, red[0]);
}

// ---------------- final: per-block softmax of the 2 scores ----------------
__global__ __launch_bounds__(256) void k_final(
    const unsigned short* __restrict__ o1, const unsigned short* __restrict__ o2,
    const float* __restrict__ score, float invN,
    const float* __restrict__ lw, const float* __restrict__ lb,
    float* __restrict__ out, int N)
{
    __shared__ float lwl[FOUT * 2];
    __shared__ float attns[2];
    const int tid = threadIdx.x;
    if (tid < FOUT * 2) lwl[tid] = lw[tid];
    if (tid == 0) {
        float s0 = score[0] * invN, s1 = score[1] * invN;
        float mm = fmaxf(s0, s1);
        float e0 = __expf(s0 - mm), e1 = __expf(s1 - mm);
        float inv = 1.f / (e0 + e1);
        attns[0] = e0 * inv;
        attns[1] = e1 * inv;
    }
    __syncthreads();
    const int n = blockIdx.x * 256 + tid;
    if (n >= N) return;
    const float a0 = attns[0], a1 = attns[1];
    float acc0 = lb[0], acc1 = lb[1];
    const uint4* p1 = (const uint4*)(o1 + (size_t)n * FOUT);
    const uint4* p2 = (const uint4*)(o2 + (size_t)n * FOUT);
    #pragma unroll
    for (int i = 0; i < FOUT / 8; i++) {   // 8 bf16 per uint4
        uint4 v1 = p1[i];
        uint4 v2 = p2[i];
        const unsigned w1[4] = {v1.x, v1.y, v1.z, v1.w};
        const unsigned w2[4] = {v2.x, v2.y, v2.z, v2.w};
        #pragma unroll
        for (int c = 0; c < 4; c++) {
            int f = i * 8 + c * 2;
            float f0 = a0 * bf2f((unsigned short)(w1[c] & 0xffff)) +
                       a1 * bf2f((unsigned short)(w2[c] & 0xffff));
            float f1 = a0 * bf2f((unsigned short)(w1[c] >> 16)) +
                       a1 * bf2f((unsigned short)(w2[c] >> 16));
            acc0 += f0 * lwl[f*2]   + f1 * lwl[(f+1)*2];
            acc1 += f0 * lwl[f*2+1] + f1 * lwl[(f+1)*2+1];
        }
    }
    *(float2*)(out + (size_t)n * 2) = make_float2(acc0, acc1);
}

extern "C" void kernel_launch(void* const* d_in, const int* in_sizes, int n_in,
                              void* d_out, int out_size, void* d_ws, size_t ws_size,
                              hipStream_t stream)
{
    const float* x_subj = (const float*)d_in[0];
    const float* x_chan = (const float*)d_in[1];
    const int*   e_cs   = (const int*)d_in[2];
    const int*   e_ss   = (const int*)d_in[3];
    const float* W_s    = (const float*)d_in[4];
    const float* b_s    = (const float*)d_in[5];
    const float* W_c    = (const float*)d_in[6];
    const float* b_c    = (const float*)d_in[7];
    const float* att_src_cs = (const float*)d_in[8];
    const float* att_dst_cs = (const float*)d_in[9];
    const float* att_src_ss = (const float*)d_in[10];
    const float* att_dst_ss = (const float*)d_in[11];
    const float* k_w  = (const float*)d_in[12];
    const float* k_b  = (const float*)d_in[13];
    const float* q    = (const float*)d_in[14];
    const float* lw   = (const float*)d_in[15];
    const float* lb   = (const float*)d_in[16];

    const int Ns  = in_sizes[0] / DIN;
    const int Nc  = in_sizes[1] / DIN;
    const int Ecs = in_sizes[2] / 2;
    const int Ess = in_sizes[3] / 2;

    const int nbin = (Ns + HR - 1) / HR;
    const int nbp = ((2 * nbin + 7) / 8) * 8;   // pad (type,bin) space to mult of 8 -> XCD pin

    // ---- workspace layout (all chunks 16B-aligned) ----
    char* p = (char*)d_ws;
    unsigned short* hbf_s = (unsigned short*)p; p += (size_t)Ns * FOUT * 2;
    unsigned short* hbf_c = (unsigned short*)p; p += (size_t)Nc * FOUT * 2;
    float* a_src_cs_ = (float*)p; p += (size_t)Nc * HH * 4;
    float* a_dst_cs_ = (float*)p; p += (size_t)Ns * HH * 4;
    float* a_src_ss_ = (float*)p; p += (size_t)Ns * HH * 4;
    float* a_dst_ss_ = (float*)p; p += (size_t)Ns * HH * 4;
    unsigned short* o1 = (unsigned short*)p; p += (size_t)Ns * FOUT * 2;
    unsigned short* o2 = (unsigned short*)p; p += (size_t)Ns * FOUT * 2;
    int* srclist_cs  = (int*)p;   p += (size_t)Ecs * 4;
    int* srclist_ss  = (int*)p;   p += (size_t)Ess * 4;
    int* rowptr_cs   = (int*)p;   p += (size_t)Ns * 4;
    int* rowptr_ss   = (int*)p;   p += (size_t)Ns * 4;
    int* deg_cs      = (int*)p;   p += (size_t)Ns * 4;
    int* deg_ss      = (int*)p;   p += (size_t)Ns * 4;
    int* bsum0       = (int*)p;   p += 2048;
    int* bsum1       = (int*)p;   p += 2048;
    int* chist       = (int*)p;   p += (size_t)2 * nbin * CHUNKN * HR * 4;  // 16 MB
    // zeroed region: score only
    float* score = (float*)p; p += 16;   // [s0, s1]
    hipMemsetAsync(score, 0, 16, stream);

    const int nbN = (Ns + 255) / 256;
    const int Nmax = Ns > Nc ? Ns : Nc;
    const int gx_lin = ((Nmax + 15) / 16 + 3) / 4;

    // feature transforms + logits (both node types), one dispatch
    k_linm<<<dim3(gx_lin, 2), dim3(256), 0, stream>>>(
        x_subj, W_s, b_s, att_dst_cs, att_src_ss, att_dst_ss,
        hbf_s, a_dst_cs_, a_src_ss_, a_dst_ss_, Ns, 3,
        x_chan, W_c, b_c, att_src_cs, att_src_cs, att_src_cs,
        hbf_c, a_src_cs_, a_src_cs_, a_src_cs_, Nc, 1);

    // CSR build, atomic-free (per-chunk histograms + LDS rank scatter), XCD-pinned bins
    k_hist<<<dim3(nbp * CHUNKN), dim3(512), 0, stream>>>(
        e_cs, Ecs, e_ss, Ess, chist, nbin, nbp);
    k_scan_block2<<<dim3(nbN, 2), dim3(256), 0, stream>>>(
        chist, rowptr_cs, bsum0, rowptr_ss, bsum1, deg_cs, deg_ss, Ns, nbin);
    k_scan_partial2<<<dim3(2), dim3(512), 0, stream>>>(bsum0, bsum1, nbN);
    k_scan_add2<<<dim3(nbN, 2), dim3(256), 0, stream>>>(rowptr_cs, bsum0, rowptr_ss, bsum1, Ns);
    k_scatb<<<dim3(nbp * CHUNKN), dim3(512), 0, stream>>>(
        e_cs, Ecs, rowptr_cs, srclist_cs,
        e_ss, Ess, rowptr_ss, srclist_ss, chist, nbin, nbp);

    // aggregation (fused softmax-normalize + relu), both metapaths
    k_agg2<<<dim3(((size_t)Ns * 32 + 255) / 256, 2), dim3(256), 0, stream>>>(
        srclist_cs, rowptr_cs, deg_cs, hbf_c, a_src_cs_, a_dst_cs_, o1,
        srclist_ss, rowptr_ss, deg_ss, hbf_s, a_src_ss_, a_dst_ss_, o2, Ns);

    // semantic attention + fuse + output
    k_sem<<<dim3(nbN, 2), dim3(256), 0, stream>>>(o1, o2, k_w, k_b, q, score, Ns);
    k_final<<<dim3(nbN), dim3(256), 0, stream>>>(
        o1, o2, score, 1.f / (float)Ns, lw, lb, (float*)d_out, Ns);
}

// Round 10
// 239.764 us; speedup vs baseline: 1.6125x; 1.1339x over previous
//
#include <hip/hip_runtime.h>

#define HH 8
#define FOUT 128
#define DIN 64
#define NCOL 160          // 128 h cols + 24 logit cols + 8 pad (10 MFMA j-tiles)
#define NSLOPE 0.2f
#define HR 8192           // dst-range per CSR bin (32 KB LDS histogram)
#define CHUNKN 20         // edge-slice chunks per bin

typedef __attribute__((ext_vector_type(8))) short bf16x8;
typedef __attribute__((ext_vector_type(4))) float f32x4;

__device__ __forceinline__ float fast_rcp(float x) { return __builtin_amdgcn_rcpf(x); }

__device__ __forceinline__ float fast_tanh(float x) {
    float ax = fabsf(x);
    float e = __expf(-2.f * ax);
    float r = (1.f - e) * fast_rcp(1.f + e);
    return x >= 0.f ? r : -r;
}

__device__ __forceinline__ unsigned short f2bf(float f) {
    unsigned u = __builtin_bit_cast(unsigned, f);
    unsigned r = (u + 0x7fffu + ((u >> 16) & 1u)) >> 16;
    return (unsigned short)r;
}

__device__ __forceinline__ float bf2f(unsigned short u) {
    return __builtin_bit_cast(float, (unsigned)u << 16);
}

// ---------------- feature transform via MFMA, logits as augmented GEMM columns ----------------
__global__ __launch_bounds__(256) void k_linm(
    const float* __restrict__ x0, const float* __restrict__ W0, const float* __restrict__ b0,
    const float* __restrict__ A00, const float* __restrict__ A01, const float* __restrict__ A02,
    unsigned short* __restrict__ h0,
    float* __restrict__ a00, float* __restrict__ a01, float* __restrict__ a02, int N0, int natt0,
    const float* __restrict__ x1, const float* __restrict__ W1, const float* __restrict__ b1,
    const float* __restrict__ A10, const float* __restrict__ A11, const float* __restrict__ A12,
    unsigned short* __restrict__ h1,
    float* __restrict__ a10, float* __restrict__ a11, float* __restrict__ a12, int N1, int natt1)
{
    const int y = blockIdx.y;
    const float* __restrict__ x  = y ? x1 : x0;
    const float* __restrict__ W  = y ? W1 : W0;
    const float* __restrict__ b  = y ? b1 : b0;
    const float* __restrict__ at0 = y ? A10 : A00;
    const float* __restrict__ at1 = y ? A11 : A01;
    const float* __restrict__ at2 = y ? A12 : A02;
    unsigned short* __restrict__ hb = y ? h1 : h0;
    float* __restrict__ a0 = y ? a10 : a00;
    float* __restrict__ a1 = y ? a11 : a01;
    float* __restrict__ a2 = y ? a12 : a02;
    const int N = y ? N1 : N0;
    const int natt = y ? natt1 : natt0;

    __shared__ unsigned short wtl[NCOL * DIN];  // W^T bf16, chunk-XOR swizzled (20 KB)
    __shared__ float attl[3][FOUT];
    __shared__ float bl[FOUT];
    __shared__ float abias[32];
    const int tid = threadIdx.x;

    if (tid < FOUT) {
        bl[tid] = b[tid];
        attl[0][tid] = at0[tid];
        attl[1][tid] = at1[tid];
        attl[2][tid] = at2[tid];
    }
    __syncthreads();

    for (int idx = tid; idx < DIN * FOUT; idx += 256) {
        int fi = idx >> 7, fo = idx & 127;
        wtl[fo * DIN + (((fi >> 3) ^ (fo & 7)) << 3) + (fi & 7)] = f2bf(W[idx]);
    }
    for (int idx = tid; idx < 2048; idx += 256) {
        int fi = idx >> 5, cs = idx & 31;
        float acc = 0.f;
        if (cs < 24) {
            int a = cs >> 3, hd = cs & 7;
            #pragma unroll
            for (int d = 0; d < 16; d++)
                acc += W[fi * FOUT + hd * 16 + d] * attl[a][hd * 16 + d];
        }
        int fo = 128 + cs;
        wtl[fo * DIN + (((fi >> 3) ^ (fo & 7)) << 3) + (fi & 7)] =
            cs < 24 ? f2bf(acc) : (unsigned short)0;
    }
    if (tid < 32) {
        float acc = 0.f;
        if (tid < 24) {
            int a = tid >> 3, hd = tid & 7;
            #pragma unroll
            for (int d = 0; d < 16; d++) acc += b[hd * 16 + d] * attl[a][hd * 16 + d];
        }
        abias[tid] = acc;
    }
    __syncthreads();

    const int w = tid >> 6, lane = tid & 63;
    const int rt = blockIdx.x * 4 + w;
    if (rt * 16 >= N) return;
    const int r16 = lane & 15, g = lane >> 4;

    int node = rt * 16 + r16;
    if (node >= N) node = N - 1;
    const float* xr = x + (size_t)node * DIN;
    bf16x8 af[2];
    #pragma unroll
    for (int kk = 0; kk < 2; kk++) {
        float4 v0 = *(const float4*)(xr + kk * 32 + g * 8);
        float4 v1 = *(const float4*)(xr + kk * 32 + g * 8 + 4);
        bf16x8 f;
        f[0] = (short)f2bf(v0.x); f[1] = (short)f2bf(v0.y);
        f[2] = (short)f2bf(v0.z); f[3] = (short)f2bf(v0.w);
        f[4] = (short)f2bf(v1.x); f[5] = (short)f2bf(v1.y);
        f[6] = (short)f2bf(v1.z); f[7] = (short)f2bf(v1.w);
        af[kk] = f;
    }

    #pragma unroll
    for (int j = 0; j < 10; j++) {
        const int fo = j * 16 + r16;
        f32x4 acc = {0.f, 0.f, 0.f, 0.f};
        #pragma unroll
        for (int kk = 0; kk < 2; kk++) {
            int c = (kk * 4 + g) ^ (fo & 7);
            bf16x8 bfr = *(bf16x8*)&wtl[fo * DIN + c * 8];
            acc = __builtin_amdgcn_mfma_f32_16x16x32_bf16(af[kk], bfr, acc, 0, 0, 0);
        }
        if (j < 8) {
            float bv = bl[fo];
            #pragma unroll
            for (int r = 0; r < 4; r++) {
                int nr = rt * 16 + g * 4 + r;
                if (nr < N) hb[(size_t)nr * FOUT + fo] = f2bf(acc[r] + bv);
            }
        } else {
            int cs = (j - 8) * 16 + r16;
            if (cs < 24) {
                int a = cs >> 3;
                if (a < natt) {
                    float* __restrict__ ga = a == 0 ? a0 : (a == 1 ? a1 : a2);
                    int hd = cs & 7;
                    float ab = abias[cs];
                    #pragma unroll
                    for (int r = 0; r < 4; r++) {
                        int nr = rt * 16 + g * 4 + r;
                        if (nr < N) ga[(size_t)nr * HH + hd] = acc[r] + ab;
                    }
                }
            }
        }
    }
}

// ---------------- CSR pass 1: per-(type,bin,chunk) histogram, dense store, NO global atomics ----
// Grid mapping bx = chunk*nbp + tb (nbp%8==0) pins each (type,bin) to one XCD.
__global__ __launch_bounds__(512) void k_hist(
    const int* __restrict__ e0, int E0, const int* __restrict__ e1, int E1,
    int* __restrict__ chist, int nbin, int nbp)
{
    const int bx = blockIdx.x;
    const int chunk = bx / nbp;
    const int tb = bx % nbp;
    if (tb >= 2 * nbin) return;
    const bool type = tb >= nbin;
    const int bin = type ? tb - nbin : tb;
    const int* __restrict__ e = type ? e1 : e0;
    const int E = type ? E1 : E0;
    const int lo = bin * HR;

    __shared__ int hist[HR];
    for (int j = threadIdx.x; j < HR; j += 512) hist[j] = 0;
    __syncthreads();

    const int per = (E + CHUNKN - 1) / CHUNKN;
    const int s0 = chunk * per;
    const int s1 = s0 + per < E ? s0 + per : E;
    for (int i = s0 + threadIdx.x; i < s1; i += 512) {
        unsigned r = (unsigned)(e[E + i] - lo);
        if (r < HR) atomicAdd(&hist[r], 1);   // LDS atomic only
    }
    __syncthreads();
    int* __restrict__ out = chist + ((size_t)tb * CHUNKN + chunk) * HR;
    for (int j = threadIdx.x; j < HR; j += 512) out[j] = hist[j];
}

// ---------------- CSR pass 2: deg from chunk-hists, block scan, per-chunk exclusive offsets ----
__global__ __launch_bounds__(256) void k_scan_block2(
    int* __restrict__ chist,
    int* __restrict__ out0, int* __restrict__ bs0,
    int* __restrict__ out1, int* __restrict__ bs1,
    int* __restrict__ d0, int* __restrict__ d1,
    int n, int nbin)
{
    const int type = blockIdx.y;
    int* __restrict__ out = type ? out1 : out0;
    int* __restrict__ bsum = type ? bs1 : bs0;
    int* __restrict__ deg = type ? d1 : d0;
    __shared__ int s[256];
    const int tid = threadIdx.x;
    const int i = blockIdx.x * 256 + tid;
    int v = 0;
    int hvals[CHUNKN];
    int* hp = nullptr;
    if (i < n) {
        const int bin = i / HR, jr = i & (HR - 1);
        hp = chist + ((size_t)(type * nbin + bin) * CHUNKN) * HR + jr;
        #pragma unroll
        for (int c = 0; c < CHUNKN; c++) { hvals[c] = hp[c * HR]; v += hvals[c]; }
    }
    s[tid] = v; __syncthreads();
    for (int off = 1; off < 256; off <<= 1) {
        int t = tid >= off ? s[tid - off] : 0;
        __syncthreads();
        s[tid] += t;
        __syncthreads();
    }
    if (i < n) {
        out[i] = s[tid] - v;          // exclusive rowptr (bsum added later)
        deg[i] = v;
        int run = 0;                  // exclusive prefix over chunks -> choff
        #pragma unroll
        for (int c = 0; c < CHUNKN; c++) { int t = hvals[c]; hp[c * HR] = run; run += t; }
    }
    if (tid == 255) bsum[blockIdx.x] = s[255];
}

__global__ __launch_bounds__(512) void k_scan_partial2(int* __restrict__ b0, int* __restrict__ b1, int nb) {
    int* bs = blockIdx.x ? b1 : b0;
    __shared__ int s[512];
    const int tid = threadIdx.x;
    int v = tid < nb ? bs[tid] : 0;
    s[tid] = v; __syncthreads();
    for (int off = 1; off < 512; off <<= 1) {
        int t = tid >= off ? s[tid - off] : 0;
        __syncthreads();
        s[tid] += t;
        __syncthreads();
    }
    if (tid < nb) bs[tid] = s[tid] - v;
}

__global__ __launch_bounds__(256) void k_scan_add2(
    int* __restrict__ o0, const int* __restrict__ b0,
    int* __restrict__ o1, const int* __restrict__ b1, int n)
{
    int* out = blockIdx.y ? o1 : o0;
    const int* bsum = blockIdx.y ? b1 : b0;
    int i = blockIdx.x * 256 + threadIdx.x;
    if (i < n) out[i] += bsum[blockIdx.x];
}

// ---------------- CSR pass 3: scatter; cnt initialized to choff so atomicAdd yields position ----
__global__ __launch_bounds__(512) void k_scatb(
    const int* __restrict__ e0, int E0, const int* __restrict__ rp0, int* __restrict__ sl0,
    const int* __restrict__ e1, int E1, const int* __restrict__ rp1, int* __restrict__ sl1,
    const int* __restrict__ chist, int nbin, int nbp)
{
    const int bx = blockIdx.x;
    const int chunk = bx / nbp;
    const int tb = bx % nbp;
    if (tb >= 2 * nbin) return;
    const bool type = tb >= nbin;
    const int bin = type ? tb - nbin : tb;
    const int* __restrict__ e = type ? e1 : e0;
    const int E = type ? E1 : E0;
    const int* __restrict__ rp = type ? rp1 : rp0;
    int* __restrict__ sl = type ? sl1 : sl0;
    const int lo = bin * HR;

    __shared__ int cnt[HR];   // 32 KB: starts at choff, atomicAdd returns choff+rank
    const int* __restrict__ cop = chist + ((size_t)tb * CHUNKN + chunk) * HR;
    for (int j = threadIdx.x; j < HR; j += 512) cnt[j] = cop[j];
    __syncthreads();

    const int per = (E + CHUNKN - 1) / CHUNKN;
    const int s0 = chunk * per;
    const int s1 = s0 + per < E ? s0 + per : E;
    for (int i = s0 + threadIdx.x; i < s1; i += 512) {
        int dst = e[E + i];
        unsigned r = (unsigned)(dst - lo);
        if (r < HR) {
            int pos = rp[dst] + atomicAdd(&cnt[r], 1);   // LDS atomic only
            sl[pos] = e[i];
        }
    }
}

// ---------------- aggregation: 32 lanes per dst, bf16 gathers, bf16 o output ----------------
__global__ __launch_bounds__(256) void k_agg2(
    const int* __restrict__ sl0, const int* __restrict__ rp0, const int* __restrict__ dg0,
    const unsigned short* __restrict__ xb0, const float* __restrict__ as0, const float* __restrict__ ad0,
    unsigned short* __restrict__ oo0,
    const int* __restrict__ sl1, const int* __restrict__ rp1, const int* __restrict__ dg1,
    const unsigned short* __restrict__ xb1, const float* __restrict__ as1, const float* __restrict__ ad1,
    unsigned short* __restrict__ oo1,
    int N)
{
    const bool m = blockIdx.y;
    const int* __restrict__ sl = m ? sl1 : sl0;
    const int* __restrict__ rp = m ? rp1 : rp0;
    const int* __restrict__ dg = m ? dg1 : dg0;
    const unsigned short* __restrict__ xb = m ? xb1 : xb0;
    const float* __restrict__ as_ = m ? as1 : as0;
    const float* __restrict__ ad_ = m ? ad1 : ad0;
    unsigned short* __restrict__ oo = m ? oo1 : oo0;

    const int t = blockIdx.x * 256 + threadIdx.x;
    const int dst = t >> 5;
    if (dst >= N) return;
    const int lane = t & 31;
    const int h = lane >> 2;
    const int d = dg[dst];
    const int base = rp[dst];
    const float adv = ad_[(size_t)dst * HH + h];
    float acc0 = 0.f, acc1 = 0.f, acc2 = 0.f, acc3 = 0.f;
    float wsum = 0.f;
    int src_next = d > 0 ? sl[base] : 0;
    for (int k = 0; k < d; k++) {
        int src = src_next;
        if (k + 1 < d) src_next = sl[base + k + 1];
        float a = as_[(size_t)src * HH + h] + adv;
        a = a > 0.f ? a : NSLOPE * a;
        float wv = __expf(a);
        uint2 xv = *(const uint2*)(xb + (size_t)src * FOUT + lane * 4);
        acc0 = fmaf(wv, bf2f((unsigned short)(xv.x & 0xffff)), acc0);
        acc1 = fmaf(wv, bf2f((unsigned short)(xv.x >> 16)), acc1);
        acc2 = fmaf(wv, bf2f((unsigned short)(xv.y & 0xffff)), acc2);
        acc3 = fmaf(wv, bf2f((unsigned short)(xv.y >> 16)), acc3);
        wsum += wv;
    }
    float inv = fast_rcp(wsum + 1e-16f);
    unsigned p0 = ((unsigned)f2bf(fmaxf(acc1 * inv, 0.f)) << 16) | f2bf(fmaxf(acc0 * inv, 0.f));
    unsigned p1 = ((unsigned)f2bf(fmaxf(acc3 * inv, 0.f)) << 16) | f2bf(fmaxf(acc2 * inv, 0.f));
    *(uint2*)(oo + (size_t)dst * FOUT + lane * 4) = make_uint2(p0, p1);
}

// ---------------- semantic score: bf16 MFMA GEMM + tanh·q reduce (o already bf16) ----------------
__global__ __launch_bounds__(256) void k_sem(
    const unsigned short* __restrict__ o1, const unsigned short* __restrict__ o2,
    const float* __restrict__ kw, const float* __restrict__ kb,
    const float* __restrict__ q, float* __restrict__ score, int N)
{
    __shared__ unsigned short kwl[FOUT * FOUT];  // kw^T bf16, chunk-XOR swizzled
    __shared__ float red[256];
    const int tid = threadIdx.x;
    const int m = blockIdx.y;
    const unsigned short* o = m ? o2 : o1;

    for (int idx = tid; idx < FOUT * FOUT; idx += 256) {
        int fi = idx >> 7, fo = idx & 127;
        int c = (fi >> 3) ^ (fo & 15);
        kwl[fo * 128 + c * 8 + (fi & 7)] = f2bf(kw[idx]);
    }
    __syncthreads();

    const int lane = tid & 63;
    const int w = tid >> 6;
    const int n0 = blockIdx.x * 256 + w * 64;
    const int r16 = lane & 15;
    const int g = lane >> 4;

    float qv[8], kbv[8];
    #pragma unroll
    for (int j = 0; j < 8; j++) { qv[j] = q[j * 16 + r16]; kbv[j] = kb[j * 16 + r16]; }

    bf16x8 afrag[4][4];
    #pragma unroll
    for (int i = 0; i < 4; i++) {
        int node = n0 + i * 16 + r16;
        if (node > N - 1) node = N - 1;
        const unsigned short* rowp = o + (size_t)node * FOUT + g * 8;
        #pragma unroll
        for (int kk = 0; kk < 4; kk++)
            afrag[i][kk] = *(const bf16x8*)(rowp + kk * 32);
    }

    float part = 0.f;
    #pragma unroll
    for (int j = 0; j < 8; j++) {
        const int fo = j * 16 + r16;
        f32x4 acc0 = {0.f,0.f,0.f,0.f}, acc1 = {0.f,0.f,0.f,0.f};
        f32x4 acc2 = {0.f,0.f,0.f,0.f}, acc3 = {0.f,0.f,0.f,0.f};
        #pragma unroll
        for (int kk = 0; kk < 4; kk++) {
            int c = (kk * 4 + g) ^ (fo & 15);
            bf16x8 bfr = *(bf16x8*)&kwl[fo * 128 + c * 8];
            acc0 = __builtin_amdgcn_mfma_f32_16x16x32_bf16(afrag[0][kk], bfr, acc0, 0, 0, 0);
            acc1 = __builtin_amdgcn_mfma_f32_16x16x32_bf16(afrag[1][kk], bfr, acc1, 0, 0, 0);
            acc2 = __builtin_amdgcn_mfma_f32_16x16x32_bf16(afrag[2][kk], bfr, acc2, 0, 0, 0);
            acc3 = __builtin_amdgcn_mfma_f32_16x16x32_bf16(afrag[3][kk], bfr, acc3, 0, 0, 0);
        }
        #pragma unroll
        for (int i = 0; i < 4; i++) {
            f32x4 a = i == 0 ? acc0 : (i == 1 ? acc1 : (i == 2 ? acc2 : acc3));
            #pragma unroll
            for (int r = 0; r < 4; r++) {
                int node = n0 + i * 16 + g * 4 + r;
                if (node < N) part += fast_tanh(a[r] + kbv[j]) * qv[j];
            }
        }
    }
    red[tid] = part;
    __syncthreads();
    for (int s2 = 128; s2 > 0; s2 >>= 1) {
        if (tid < s2) red[tid] += red[tid + s2];
        __syncthreads();
    }
    if (tid == 0) atomicAdd(score + m, red[0]);
}

// ---------------- final: per-block softmax of the 2 scores ----------------
__global__ __launch_bounds__(256) void k_final(
    const unsigned short* __restrict__ o1, const unsigned short* __restrict__ o2,
    const float* __restrict__ score, float invN,
    const float* __restrict__ lw, const float* __restrict__ lb,
    float* __restrict__ out, int N)
{
    __shared__ float lwl[FOUT * 2];
    __shared__ float attns[2];
    const int tid = threadIdx.x;
    if (tid < FOUT * 2) lwl[tid] = lw[tid];
    if (tid == 0) {
        float s0 = score[0] * invN, s1 = score[1] * invN;
        float mm = fmaxf(s0, s1);
        float e0 = __expf(s0 - mm), e1 = __expf(s1 - mm);
        float inv = 1.f / (e0 + e1);
        attns[0] = e0 * inv;
        attns[1] = e1 * inv;
    }
    __syncthreads();
    const int n = blockIdx.x * 256 + tid;
    if (n >= N) return;
    const float a0 = attns[0], a1 = attns[1];
    float acc0 = lb[0], acc1 = lb[1];
    const uint4* p1 = (const uint4*)(o1 + (size_t)n * FOUT);
    const uint4* p2 = (const uint4*)(o2 + (size_t)n * FOUT);
    #pragma unroll
    for (int i = 0; i < FOUT / 8; i++) {   // 8 bf16 per uint4
        uint4 v1 = p1[i];
        uint4 v2 = p2[i];
        const unsigned w1[4] = {v1.x, v1.y, v1.z, v1.w};
        const unsigned w2[4] = {v2.x, v2.y, v2.z, v2.w};
        #pragma unroll
        for (int c = 0; c < 4; c++) {
            int f = i * 8 + c * 2;
            float f0 = a0 * bf2f((unsigned short)(w1[c] & 0xffff)) +
                       a1 * bf2f((unsigned short)(w2[c] & 0xffff));
            float f1 = a0 * bf2f((unsigned short)(w1[c] >> 16)) +
                       a1 * bf2f((unsigned short)(w2[c] >> 16));
            acc0 += f0 * lwl[f*2]   + f1 * lwl[(f+1)*2];
            acc1 += f0 * lwl[f*2+1] + f1 * lwl[(f+1)*2+1];
        }
    }
    *(float2*)(out + (size_t)n * 2) = make_float2(acc0, acc1);
}

extern "C" void kernel_launch(void* const* d_in, const int* in_sizes, int n_in,
                              void* d_out, int out_size, void* d_ws, size_t ws_size,
                              hipStream_t stream)
{
    const float* x_subj = (const float*)d_in[0];
    const float* x_chan = (const float*)d_in[1];
    const int*   e_cs   = (const int*)d_in[2];
    const int*   e_ss   = (const int*)d_in[3];
    const float* W_s    = (const float*)d_in[4];
    const float* b_s    = (const float*)d_in[5];
    const float* W_c    = (const float*)d_in[6];
    const float* b_c    = (const float*)d_in[7];
    const float* att_src_cs = (const float*)d_in[8];
    const float* att_dst_cs = (const float*)d_in[9];
    const float* att_src_ss = (const float*)d_in[10];
    const float* att_dst_ss = (const float*)d_in[11];
    const float* k_w  = (const float*)d_in[12];
    const float* k_b  = (const float*)d_in[13];
    const float* q    = (const float*)d_in[14];
    const float* lw   = (const float*)d_in[15];
    const float* lb   = (const float*)d_in[16];

    const int Ns  = in_sizes[0] / DIN;
    const int Nc  = in_sizes[1] / DIN;
    const int Ecs = in_sizes[2] / 2;
    const int Ess = in_sizes[3] / 2;

    const int nbin = (Ns + HR - 1) / HR;
    const int nbp = ((2 * nbin + 7) / 8) * 8;   // pad (type,bin) space to mult of 8 -> XCD pin

    // ---- workspace layout (all chunks 16B-aligned) ----
    char* p = (char*)d_ws;
    unsigned short* hbf_s = (unsigned short*)p; p += (size_t)Ns * FOUT * 2;
    unsigned short* hbf_c = (unsigned short*)p; p += (size_t)Nc * FOUT * 2;
    float* a_src_cs_ = (float*)p; p += (size_t)Nc * HH * 4;
    float* a_dst_cs_ = (float*)p; p += (size_t)Ns * HH * 4;
    float* a_src_ss_ = (float*)p; p += (size_t)Ns * HH * 4;
    float* a_dst_ss_ = (float*)p; p += (size_t)Ns * HH * 4;
    unsigned short* o1 = (unsigned short*)p; p += (size_t)Ns * FOUT * 2;
    unsigned short* o2 = (unsigned short*)p; p += (size_t)Ns * FOUT * 2;
    int* srclist_cs  = (int*)p;   p += (size_t)Ecs * 4;
    int* srclist_ss  = (int*)p;   p += (size_t)Ess * 4;
    int* rowptr_cs   = (int*)p;   p += (size_t)Ns * 4;
    int* rowptr_ss   = (int*)p;   p += (size_t)Ns * 4;
    int* deg_cs      = (int*)p;   p += (size_t)Ns * 4;
    int* deg_ss      = (int*)p;   p += (size_t)Ns * 4;
    int* bsum0       = (int*)p;   p += 2048;
    int* bsum1       = (int*)p;   p += 2048;
    int* chist       = (int*)p;   p += (size_t)2 * nbin * CHUNKN * HR * 4;  // ~17 MB
    // zeroed region: score only
    float* score = (float*)p; p += 16;   // [s0, s1]
    hipMemsetAsync(score, 0, 16, stream);

    const int nbN = (Ns + 255) / 256;
    const int Nmax = Ns > Nc ? Ns : Nc;
    const int gx_lin = ((Nmax + 15) / 16 + 3) / 4;

    // feature transforms + logits (both node types), one dispatch
    k_linm<<<dim3(gx_lin, 2), dim3(256), 0, stream>>>(
        x_subj, W_s, b_s, att_dst_cs, att_src_ss, att_dst_ss,
        hbf_s, a_dst_cs_, a_src_ss_, a_dst_ss_, Ns, 3,
        x_chan, W_c, b_c, att_src_cs, att_src_cs, att_src_cs,
        hbf_c, a_src_cs_, a_src_cs_, a_src_cs_, Nc, 1);

    // CSR build, atomic-free (per-chunk histograms + LDS rank scatter), XCD-pinned bins
    k_hist<<<dim3(nbp * CHUNKN), dim3(512), 0, stream>>>(
        e_cs, Ecs, e_ss, Ess, chist, nbin, nbp);
    k_scan_block2<<<dim3(nbN, 2), dim3(256), 0, stream>>>(
        chist, rowptr_cs, bsum0, rowptr_ss, bsum1, deg_cs, deg_ss, Ns, nbin);
    k_scan_partial2<<<dim3(2), dim3(512), 0, stream>>>(bsum0, bsum1, nbN);
    k_scan_add2<<<dim3(nbN, 2), dim3(256), 0, stream>>>(rowptr_cs, bsum0, rowptr_ss, bsum1, Ns);
    k_scatb<<<dim3(nbp * CHUNKN), dim3(512), 0, stream>>>(
        e_cs, Ecs, rowptr_cs, srclist_cs,
        e_ss, Ess, rowptr_ss, srclist_ss, chist, nbin, nbp);

    // aggregation (fused softmax-normalize + relu), both metapaths
    k_agg2<<<dim3(((size_t)Ns * 32 + 255) / 256, 2), dim3(256), 0, stream>>>(
        srclist_cs, rowptr_cs, deg_cs, hbf_c, a_src_cs_, a_dst_cs_, o1,
        srclist_ss, rowptr_ss, deg_ss, hbf_s, a_src_ss_, a_dst_ss_, o2, Ns);

    // semantic attention + fuse + output
    k_sem<<<dim3(nbN, 2), dim3(256), 0, stream>>>(o1, o2, k_w, k_b, q, score, Ns);
    k_final<<<dim3(nbN), dim3(256), 0, stream>>>(
        o1, o2, score, 1.f / (float)Ns, lw, lb, (float*)d_out, Ns);
}

// Round 11
// 233.222 us; speedup vs baseline: 1.6577x; 1.0280x over previous
//
#include <hip/hip_runtime.h>

#define HH 8
#define FOUT 128
#define DIN 64
#define NCOL 160          // 128 h cols + 24 logit cols + 8 pad (10 MFMA j-tiles)
#define NSLOPE 0.2f
#define HR 8192           // dst-range per CSR bin (32 KB LDS histogram)
#define CHUNKN 20         // edge-slice chunks per bin

typedef __attribute__((ext_vector_type(8))) short bf16x8;
typedef __attribute__((ext_vector_type(4))) float f32x4;

__device__ __forceinline__ float fast_rcp(float x) { return __builtin_amdgcn_rcpf(x); }

__device__ __forceinline__ float fast_tanh(float x) {
    float ax = fabsf(x);
    float e = __expf(-2.f * ax);
    float r = (1.f - e) * fast_rcp(1.f + e);
    return x >= 0.f ? r : -r;
}

__device__ __forceinline__ unsigned short f2bf(float f) {
    unsigned u = __builtin_bit_cast(unsigned, f);
    unsigned r = (u + 0x7fffu + ((u >> 16) & 1u)) >> 16;
    return (unsigned short)r;
}

__device__ __forceinline__ float bf2f(unsigned short u) {
    return __builtin_bit_cast(float, (unsigned)u << 16);
}

// ---------------- feature transform via MFMA, logits as augmented GEMM columns ----------------
__global__ __launch_bounds__(256) void k_linm(
    const float* __restrict__ x0, const float* __restrict__ W0, const float* __restrict__ b0,
    const float* __restrict__ A00, const float* __restrict__ A01, const float* __restrict__ A02,
    unsigned short* __restrict__ h0,
    float* __restrict__ a00, float* __restrict__ a01, float* __restrict__ a02, int N0, int natt0,
    const float* __restrict__ x1, const float* __restrict__ W1, const float* __restrict__ b1,
    const float* __restrict__ A10, const float* __restrict__ A11, const float* __restrict__ A12,
    unsigned short* __restrict__ h1,
    float* __restrict__ a10, float* __restrict__ a11, float* __restrict__ a12, int N1, int natt1)
{
    const int y = blockIdx.y;
    const float* __restrict__ x  = y ? x1 : x0;
    const float* __restrict__ W  = y ? W1 : W0;
    const float* __restrict__ b  = y ? b1 : b0;
    const float* __restrict__ at0 = y ? A10 : A00;
    const float* __restrict__ at1 = y ? A11 : A01;
    const float* __restrict__ at2 = y ? A12 : A02;
    unsigned short* __restrict__ hb = y ? h1 : h0;
    float* __restrict__ a0 = y ? a10 : a00;
    float* __restrict__ a1 = y ? a11 : a01;
    float* __restrict__ a2 = y ? a12 : a02;
    const int N = y ? N1 : N0;
    const int natt = y ? natt1 : natt0;

    __shared__ unsigned short wtl[NCOL * DIN];  // W^T bf16, chunk-XOR swizzled (20 KB)
    __shared__ float attl[3][FOUT];
    __shared__ float bl[FOUT];
    __shared__ float abias[32];
    const int tid = threadIdx.x;

    if (tid < FOUT) {
        bl[tid] = b[tid];
        attl[0][tid] = at0[tid];
        attl[1][tid] = at1[tid];
        attl[2][tid] = at2[tid];
    }
    __syncthreads();

    for (int idx = tid; idx < DIN * FOUT; idx += 256) {
        int fi = idx >> 7, fo = idx & 127;
        wtl[fo * DIN + (((fi >> 3) ^ (fo & 7)) << 3) + (fi & 7)] = f2bf(W[idx]);
    }
    for (int idx = tid; idx < 2048; idx += 256) {
        int fi = idx >> 5, cs = idx & 31;
        float acc = 0.f;
        if (cs < 24) {
            int a = cs >> 3, hd = cs & 7;
            #pragma unroll
            for (int d = 0; d < 16; d++)
                acc += W[fi * FOUT + hd * 16 + d] * attl[a][hd * 16 + d];
        }
        int fo = 128 + cs;
        wtl[fo * DIN + (((fi >> 3) ^ (fo & 7)) << 3) + (fi & 7)] =
            cs < 24 ? f2bf(acc) : (unsigned short)0;
    }
    if (tid < 32) {
        float acc = 0.f;
        if (tid < 24) {
            int a = tid >> 3, hd = tid & 7;
            #pragma unroll
            for (int d = 0; d < 16; d++) acc += b[hd * 16 + d] * attl[a][hd * 16 + d];
        }
        abias[tid] = acc;
    }
    __syncthreads();

    const int w = tid >> 6, lane = tid & 63;
    const int rt = blockIdx.x * 4 + w;
    if (rt * 16 >= N) return;
    const int r16 = lane & 15, g = lane >> 4;

    int node = rt * 16 + r16;
    if (node >= N) node = N - 1;
    const float* xr = x + (size_t)node * DIN;
    bf16x8 af[2];
    #pragma unroll
    for (int kk = 0; kk < 2; kk++) {
        float4 v0 = *(const float4*)(xr + kk * 32 + g * 8);
        float4 v1 = *(const float4*)(xr + kk * 32 + g * 8 + 4);
        bf16x8 f;
        f[0] = (short)f2bf(v0.x); f[1] = (short)f2bf(v0.y);
        f[2] = (short)f2bf(v0.z); f[3] = (short)f2bf(v0.w);
        f[4] = (short)f2bf(v1.x); f[5] = (short)f2bf(v1.y);
        f[6] = (short)f2bf(v1.z); f[7] = (short)f2bf(v1.w);
        af[kk] = f;
    }

    #pragma unroll
    for (int j = 0; j < 10; j++) {
        const int fo = j * 16 + r16;
        f32x4 acc = {0.f, 0.f, 0.f, 0.f};
        #pragma unroll
        for (int kk = 0; kk < 2; kk++) {
            int c = (kk * 4 + g) ^ (fo & 7);
            bf16x8 bfr = *(bf16x8*)&wtl[fo * DIN + c * 8];
            acc = __builtin_amdgcn_mfma_f32_16x16x32_bf16(af[kk], bfr, acc, 0, 0, 0);
        }
        if (j < 8) {
            float bv = bl[fo];
            #pragma unroll
            for (int r = 0; r < 4; r++) {
                int nr = rt * 16 + g * 4 + r;
                if (nr < N) hb[(size_t)nr * FOUT + fo] = f2bf(acc[r] + bv);
            }
        } else {
            int cs = (j - 8) * 16 + r16;
            if (cs < 24) {
                int a = cs >> 3;
                if (a < natt) {
                    float* __restrict__ ga = a == 0 ? a0 : (a == 1 ? a1 : a2);
                    int hd = cs & 7;
                    float ab = abias[cs];
                    #pragma unroll
                    for (int r = 0; r < 4; r++) {
                        int nr = rt * 16 + g * 4 + r;
                        if (nr < N) ga[(size_t)nr * HH + hd] = acc[r] + ab;
                    }
                }
            }
        }
    }
}

// ---------------- CSR pass 1: per-(type,bin,chunk) histogram, dense store, NO global atomics ----
// Grid mapping bx = chunk*nbp + tb (nbp%8==0) pins each (type,bin) to one XCD.
__global__ __launch_bounds__(512) void k_hist(
    const int* __restrict__ e0, int E0, const int* __restrict__ e1, int E1,
    int* __restrict__ chist, int nbin, int nbp)
{
    const int bx = blockIdx.x;
    const int chunk = bx / nbp;
    const int tb = bx % nbp;
    if (tb >= 2 * nbin) return;
    const bool type = tb >= nbin;
    const int bin = type ? tb - nbin : tb;
    const int* __restrict__ e = type ? e1 : e0;
    const int E = type ? E1 : E0;
    const int lo = bin * HR;

    __shared__ int hist[HR];
    for (int j = threadIdx.x; j < HR; j += 512) hist[j] = 0;
    __syncthreads();

    const int per = (E + CHUNKN - 1) / CHUNKN;
    const int s0 = chunk * per;
    const int s1 = s0 + per < E ? s0 + per : E;
    for (int i = s0 + threadIdx.x; i < s1; i += 512) {
        unsigned r = (unsigned)(e[E + i] - lo);
        if (r < HR) atomicAdd(&hist[r], 1);   // LDS atomic only
    }
    __syncthreads();
    int* __restrict__ out = chist + ((size_t)tb * CHUNKN + chunk) * HR;
    for (int j = threadIdx.x; j < HR; j += 512) out[j] = hist[j];
}

// ---------------- CSR pass 2: deg from chunk-hists, block scan, per-chunk exclusive offsets ----
__global__ __launch_bounds__(256) void k_scan_block2(
    int* __restrict__ chist,
    int* __restrict__ out0, int* __restrict__ bs0,
    int* __restrict__ out1, int* __restrict__ bs1,
    int* __restrict__ d0, int* __restrict__ d1,
    int n, int nbin)
{
    const int type = blockIdx.y;
    int* __restrict__ out = type ? out1 : out0;
    int* __restrict__ bsum = type ? bs1 : bs0;
    int* __restrict__ deg = type ? d1 : d0;
    __shared__ int s[256];
    const int tid = threadIdx.x;
    const int i = blockIdx.x * 256 + tid;
    int v = 0;
    int hvals[CHUNKN];
    int* hp = nullptr;
    if (i < n) {
        const int bin = i / HR, jr = i & (HR - 1);
        hp = chist + ((size_t)(type * nbin + bin) * CHUNKN) * HR + jr;
        #pragma unroll
        for (int c = 0; c < CHUNKN; c++) { hvals[c] = hp[c * HR]; v += hvals[c]; }
    }
    s[tid] = v; __syncthreads();
    for (int off = 1; off < 256; off <<= 1) {
        int t = tid >= off ? s[tid - off] : 0;
        __syncthreads();
        s[tid] += t;
        __syncthreads();
    }
    if (i < n) {
        out[i] = s[tid] - v;          // exclusive rowptr (block-prefix added later)
        deg[i] = v;
        int run = 0;                  // exclusive prefix over chunks -> choff
        #pragma unroll
        for (int c = 0; c < CHUNKN; c++) { int t = hvals[c]; hp[c * HR] = run; run += t; }
    }
    if (tid == 255) bsum[blockIdx.x] = s[255];
}

// ---------------- CSR pass 2b: add block prefix (each block self-reduces raw bsum) ----------------
__global__ __launch_bounds__(256) void k_scan_add2(
    int* __restrict__ o0, const int* __restrict__ b0,
    int* __restrict__ o1, const int* __restrict__ b1, int n)
{
    int* __restrict__ out = blockIdx.y ? o1 : o0;
    const int* __restrict__ bsum = blockIdx.y ? b1 : b0;
    __shared__ int s[256];
    const int tid = threadIdx.x;
    const int bx = blockIdx.x;
    int acc = 0;
    for (int j = tid; j < bx; j += 256) acc += bsum[j];
    s[tid] = acc; __syncthreads();
    for (int w = 128; w > 0; w >>= 1) {
        if (tid < w) s[tid] += s[tid + w];
        __syncthreads();
    }
    const int pre = s[0];
    const int i = bx * 256 + tid;
    if (i < n) out[i] += pre;
}

// ---------------- CSR pass 3: scatter; cnt initialized to choff so atomicAdd yields position ----
__global__ __launch_bounds__(512) void k_scatb(
    const int* __restrict__ e0, int E0, const int* __restrict__ rp0, int* __restrict__ sl0,
    const int* __restrict__ e1, int E1, const int* __restrict__ rp1, int* __restrict__ sl1,
    const int* __restrict__ chist, int nbin, int nbp)
{
    const int bx = blockIdx.x;
    const int chunk = bx / nbp;
    const int tb = bx % nbp;
    if (tb >= 2 * nbin) return;
    const bool type = tb >= nbin;
    const int bin = type ? tb - nbin : tb;
    const int* __restrict__ e = type ? e1 : e0;
    const int E = type ? E1 : E0;
    const int* __restrict__ rp = type ? rp1 : rp0;
    int* __restrict__ sl = type ? sl1 : sl0;
    const int lo = bin * HR;

    __shared__ int cnt[HR];   // 32 KB: starts at choff, atomicAdd returns choff+rank
    const int* __restrict__ cop = chist + ((size_t)tb * CHUNKN + chunk) * HR;
    for (int j = threadIdx.x; j < HR; j += 512) cnt[j] = cop[j];
    __syncthreads();

    const int per = (E + CHUNKN - 1) / CHUNKN;
    const int s0 = chunk * per;
    const int s1 = s0 + per < E ? s0 + per : E;
    for (int i = s0 + threadIdx.x; i < s1; i += 512) {
        int dst = e[E + i];
        unsigned r = (unsigned)(dst - lo);
        if (r < HR) {
            int pos = rp[dst] + atomicAdd(&cnt[r], 1);   // LDS atomic only
            sl[pos] = e[i];
        }
    }
}

// ---------------- aggregation: 32 lanes per dst, bf16 gathers, bf16 o output ----------------
__global__ __launch_bounds__(256) void k_agg2(
    const int* __restrict__ sl0, const int* __restrict__ rp0, const int* __restrict__ dg0,
    const unsigned short* __restrict__ xb0, const float* __restrict__ as0, const float* __restrict__ ad0,
    unsigned short* __restrict__ oo0,
    const int* __restrict__ sl1, const int* __restrict__ rp1, const int* __restrict__ dg1,
    const unsigned short* __restrict__ xb1, const float* __restrict__ as1, const float* __restrict__ ad1,
    unsigned short* __restrict__ oo1,
    int N)
{
    const bool m = blockIdx.y;
    const int* __restrict__ sl = m ? sl1 : sl0;
    const int* __restrict__ rp = m ? rp1 : rp0;
    const int* __restrict__ dg = m ? dg1 : dg0;
    const unsigned short* __restrict__ xb = m ? xb1 : xb0;
    const float* __restrict__ as_ = m ? as1 : as0;
    const float* __restrict__ ad_ = m ? ad1 : ad0;
    unsigned short* __restrict__ oo = m ? oo1 : oo0;

    const int t = blockIdx.x * 256 + threadIdx.x;
    const int dst = t >> 5;
    if (dst >= N) return;
    const int lane = t & 31;
    const int h = lane >> 2;
    const int d = dg[dst];
    const int base = rp[dst];
    const float adv = ad_[(size_t)dst * HH + h];
    float acc0 = 0.f, acc1 = 0.f, acc2 = 0.f, acc3 = 0.f;
    float wsum = 0.f;
    int src_next = d > 0 ? sl[base] : 0;
    for (int k = 0; k < d; k++) {
        int src = src_next;
        if (k + 1 < d) src_next = sl[base + k + 1];
        float a = as_[(size_t)src * HH + h] + adv;
        a = a > 0.f ? a : NSLOPE * a;
        float wv = __expf(a);
        uint2 xv = *(const uint2*)(xb + (size_t)src * FOUT + lane * 4);
        acc0 = fmaf(wv, bf2f((unsigned short)(xv.x & 0xffff)), acc0);
        acc1 = fmaf(wv, bf2f((unsigned short)(xv.x >> 16)), acc1);
        acc2 = fmaf(wv, bf2f((unsigned short)(xv.y & 0xffff)), acc2);
        acc3 = fmaf(wv, bf2f((unsigned short)(xv.y >> 16)), acc3);
        wsum += wv;
    }
    float inv = fast_rcp(wsum + 1e-16f);
    unsigned p0 = ((unsigned)f2bf(fmaxf(acc1 * inv, 0.f)) << 16) | f2bf(fmaxf(acc0 * inv, 0.f));
    unsigned p1 = ((unsigned)f2bf(fmaxf(acc3 * inv, 0.f)) << 16) | f2bf(fmaxf(acc2 * inv, 0.f));
    *(uint2*)(oo + (size_t)dst * FOUT + lane * 4) = make_uint2(p0, p1);
}

// ---------------- semantic score: both metapaths per block (kwl staged once) ----------------
__global__ __launch_bounds__(256) void k_sem(
    const unsigned short* __restrict__ o1p, const unsigned short* __restrict__ o2p,
    const float* __restrict__ kw, const float* __restrict__ kb,
    const float* __restrict__ q, float* __restrict__ score, int N)
{
    __shared__ unsigned short kwl[FOUT * FOUT];  // kw^T bf16, chunk-XOR swizzled
    __shared__ float red[256];
    const int tid = threadIdx.x;

    for (int idx = tid; idx < FOUT * FOUT; idx += 256) {
        int fi = idx >> 7, fo = idx & 127;
        int c = (fi >> 3) ^ (fo & 15);
        kwl[fo * 128 + c * 8 + (fi & 7)] = f2bf(kw[idx]);
    }
    __syncthreads();

    const int lane = tid & 63;
    const int w = tid >> 6;
    const int n0 = blockIdx.x * 256 + w * 64;
    const int r16 = lane & 15;
    const int g = lane >> 4;

    float qv[8], kbv[8];
    #pragma unroll
    for (int j = 0; j < 8; j++) { qv[j] = q[j * 16 + r16]; kbv[j] = kb[j * 16 + r16]; }

    for (int m = 0; m < 2; m++) {
        const unsigned short* __restrict__ o = m ? o2p : o1p;
        bf16x8 afrag[4][4];
        #pragma unroll
        for (int i = 0; i < 4; i++) {
            int node = n0 + i * 16 + r16;
            if (node > N - 1) node = N - 1;
            const unsigned short* rowp = o + (size_t)node * FOUT + g * 8;
            #pragma unroll
            for (int kk = 0; kk < 4; kk++)
                afrag[i][kk] = *(const bf16x8*)(rowp + kk * 32);
        }

        float part = 0.f;
        #pragma unroll
        for (int j = 0; j < 8; j++) {
            const int fo = j * 16 + r16;
            f32x4 acc0 = {0.f,0.f,0.f,0.f}, acc1 = {0.f,0.f,0.f,0.f};
            f32x4 acc2 = {0.f,0.f,0.f,0.f}, acc3 = {0.f,0.f,0.f,0.f};
            #pragma unroll
            for (int kk = 0; kk < 4; kk++) {
                int c = (kk * 4 + g) ^ (fo & 15);
                bf16x8 bfr = *(bf16x8*)&kwl[fo * 128 + c * 8];
                acc0 = __builtin_amdgcn_mfma_f32_16x16x32_bf16(afrag[0][kk], bfr, acc0, 0, 0, 0);
                acc1 = __builtin_amdgcn_mfma_f32_16x16x32_bf16(afrag[1][kk], bfr, acc1, 0, 0, 0);
                acc2 = __builtin_amdgcn_mfma_f32_16x16x32_bf16(afrag[2][kk], bfr, acc2, 0, 0, 0);
                acc3 = __builtin_amdgcn_mfma_f32_16x16x32_bf16(afrag[3][kk], bfr, acc3, 0, 0, 0);
            }
            #pragma unroll
            for (int i = 0; i < 4; i++) {
                f32x4 a = i == 0 ? acc0 : (i == 1 ? acc1 : (i == 2 ? acc2 : acc3));
                #pragma unroll
                for (int r = 0; r < 4; r++) {
                    int node = n0 + i * 16 + g * 4 + r;
                    if (node < N) part += fast_tanh(a[r] + kbv[j]) * qv[j];
                }
            }
        }
        red[tid] = part;
        __syncthreads();
        for (int s2 = 128; s2 > 0; s2 >>= 1) {
            if (tid < s2) red[tid] += red[tid + s2];
            __syncthreads();
        }
        if (tid == 0) atomicAdd(score + m, red[0]);
        __syncthreads();
    }
}

// ---------------- final: per-block softmax of the 2 scores ----------------
__global__ __launch_bounds__(256) void k_final(
    const unsigned short* __restrict__ o1, const unsigned short* __restrict__ o2,
    const float* __restrict__ score, float invN,
    const float* __restrict__ lw, const float* __restrict__ lb,
    float* __restrict__ out, int N)
{
    __shared__ float lwl[FOUT * 2];
    __shared__ float attns[2];
    const int tid = threadIdx.x;
    if (tid < FOUT * 2) lwl[tid] = lw[tid];
    if (tid == 0) {
        float s0 = score[0] * invN, s1 = score[1] * invN;
        float mm = fmaxf(s0, s1);
        float e0 = __expf(s0 - mm), e1 = __expf(s1 - mm);
        float inv = 1.f / (e0 + e1);
        attns[0] = e0 * inv;
        attns[1] = e1 * inv;
    }
    __syncthreads();
    const int n = blockIdx.x * 256 + tid;
    if (n >= N) return;
    const float a0 = attns[0], a1 = attns[1];
    float acc0 = lb[0], acc1 = lb[1];
    const uint4* p1 = (const uint4*)(o1 + (size_t)n * FOUT);
    const uint4* p2 = (const uint4*)(o2 + (size_t)n * FOUT);
    #pragma unroll
    for (int i = 0; i < FOUT / 8; i++) {   // 8 bf16 per uint4
        uint4 v1 = p1[i];
        uint4 v2 = p2[i];
        const unsigned w1[4] = {v1.x, v1.y, v1.z, v1.w};
        const unsigned w2[4] = {v2.x, v2.y, v2.z, v2.w};
        #pragma unroll
        for (int c = 0; c < 4; c++) {
            int f = i * 8 + c * 2;
            float f0 = a0 * bf2f((unsigned short)(w1[c] & 0xffff)) +
                       a1 * bf2f((unsigned short)(w2[c] & 0xffff));
            float f1 = a0 * bf2f((unsigned short)(w1[c] >> 16)) +
                       a1 * bf2f((unsigned short)(w2[c] >> 16));
            acc0 += f0 * lwl[f*2]   + f1 * lwl[(f+1)*2];
            acc1 += f0 * lwl[f*2+1] + f1 * lwl[(f+1)*2+1];
        }
    }
    *(float2*)(out + (size_t)n * 2) = make_float2(acc0, acc1);
}

extern "C" void kernel_launch(void* const* d_in, const int* in_sizes, int n_in,
                              void* d_out, int out_size, void* d_ws, size_t ws_size,
                              hipStream_t stream)
{
    const float* x_subj = (const float*)d_in[0];
    const float* x_chan = (const float*)d_in[1];
    const int*   e_cs   = (const int*)d_in[2];
    const int*   e_ss   = (const int*)d_in[3];
    const float* W_s    = (const float*)d_in[4];
    const float* b_s    = (const float*)d_in[5];
    const float* W_c    = (const float*)d_in[6];
    const float* b_c    = (const float*)d_in[7];
    const float* att_src_cs = (const float*)d_in[8];
    const float* att_dst_cs = (const float*)d_in[9];
    const float* att_src_ss = (const float*)d_in[10];
    const float* att_dst_ss = (const float*)d_in[11];
    const float* k_w  = (const float*)d_in[12];
    const float* k_b  = (const float*)d_in[13];
    const float* q    = (const float*)d_in[14];
    const float* lw   = (const float*)d_in[15];
    const float* lb   = (const float*)d_in[16];

    const int Ns  = in_sizes[0] / DIN;
    const int Nc  = in_sizes[1] / DIN;
    const int Ecs = in_sizes[2] / 2;
    const int Ess = in_sizes[3] / 2;

    const int nbin = (Ns + HR - 1) / HR;
    const int nbp = ((2 * nbin + 7) / 8) * 8;   // pad (type,bin) space to mult of 8 -> XCD pin

    // ---- workspace layout (all chunks 16B-aligned) ----
    char* p = (char*)d_ws;
    unsigned short* hbf_s = (unsigned short*)p; p += (size_t)Ns * FOUT * 2;
    unsigned short* hbf_c = (unsigned short*)p; p += (size_t)Nc * FOUT * 2;
    float* a_src_cs_ = (float*)p; p += (size_t)Nc * HH * 4;
    float* a_dst_cs_ = (float*)p; p += (size_t)Ns * HH * 4;
    float* a_src_ss_ = (float*)p; p += (size_t)Ns * HH * 4;
    float* a_dst_ss_ = (float*)p; p += (size_t)Ns * HH * 4;
    unsigned short* o1 = (unsigned short*)p; p += (size_t)Ns * FOUT * 2;
    unsigned short* o2 = (unsigned short*)p; p += (size_t)Ns * FOUT * 2;
    int* srclist_cs  = (int*)p;   p += (size_t)Ecs * 4;
    int* srclist_ss  = (int*)p;   p += (size_t)Ess * 4;
    int* rowptr_cs   = (int*)p;   p += (size_t)Ns * 4;
    int* rowptr_ss   = (int*)p;   p += (size_t)Ns * 4;
    int* deg_cs      = (int*)p;   p += (size_t)Ns * 4;
    int* deg_ss      = (int*)p;   p += (size_t)Ns * 4;
    int* bsum0       = (int*)p;   p += 2048;
    int* bsum1       = (int*)p;   p += 2048;
    int* chist       = (int*)p;   p += (size_t)2 * nbin * CHUNKN * HR * 4;  // ~17 MB
    // zeroed region: score only
    float* score = (float*)p; p += 16;   // [s0, s1]
    hipMemsetAsync(score, 0, 16, stream);

    const int nbN = (Ns + 255) / 256;
    const int Nmax = Ns > Nc ? Ns : Nc;
    const int gx_lin = ((Nmax + 15) / 16 + 3) / 4;

    // feature transforms + logits (both node types), one dispatch
    k_linm<<<dim3(gx_lin, 2), dim3(256), 0, stream>>>(
        x_subj, W_s, b_s, att_dst_cs, att_src_ss, att_dst_ss,
        hbf_s, a_dst_cs_, a_src_ss_, a_dst_ss_, Ns, 3,
        x_chan, W_c, b_c, att_src_cs, att_src_cs, att_src_cs,
        hbf_c, a_src_cs_, a_src_cs_, a_src_cs_, Nc, 1);

    // CSR build, atomic-free (per-chunk histograms + LDS rank scatter), XCD-pinned bins
    k_hist<<<dim3(nbp * CHUNKN), dim3(512), 0, stream>>>(
        e_cs, Ecs, e_ss, Ess, chist, nbin, nbp);
    k_scan_block2<<<dim3(nbN, 2), dim3(256), 0, stream>>>(
        chist, rowptr_cs, bsum0, rowptr_ss, bsum1, deg_cs, deg_ss, Ns, nbin);
    k_scan_add2<<<dim3(nbN, 2), dim3(256), 0, stream>>>(rowptr_cs, bsum0, rowptr_ss, bsum1, Ns);
    k_scatb<<<dim3(nbp * CHUNKN), dim3(512), 0, stream>>>(
        e_cs, Ecs, rowptr_cs, srclist_cs,
        e_ss, Ess, rowptr_ss, srclist_ss, chist, nbin, nbp);

    // aggregation (fused softmax-normalize + relu), both metapaths
    k_agg2<<<dim3(((size_t)Ns * 32 + 255) / 256, 2), dim3(256), 0, stream>>>(
        srclist_cs, rowptr_cs, deg_cs, hbf_c, a_src_cs_, a_dst_cs_, o1,
        srclist_ss, rowptr_ss, deg_ss, hbf_s, a_src_ss_, a_dst_ss_, o2, Ns);

    // semantic attention + fuse + output
    k_sem<<<dim3(nbN), dim3(256), 0, stream>>>(o1, o2, k_w, k_b, q, score, Ns);
    k_final<<<dim3(nbN), dim3(256), 0, stream>>>(
        o1, o2, score, 1.f / (float)Ns, lw, lb, (float*)d_out, Ns);
}

// Round 12
// 220.211 us; speedup vs baseline: 1.7556x; 1.0591x over previous
//
#include <hip/hip_runtime.h>

#define HH 8
#define FOUT 128
#define DIN 64
#define NCOL 160          // 128 h cols + 24 logit cols + 8 pad (10 MFMA j-tiles)
#define SEMR 144          // k_sem B rows: 128 kw cols + 2 lin_w cols + 14 pad (9 j-tiles)
#define NSLOPE 0.2f
#define HR 8192           // dst-range per CSR bin (32 KB LDS histogram)
#define CHUNKN 20         // edge-slice chunks per bin

typedef __attribute__((ext_vector_type(8))) short bf16x8;
typedef __attribute__((ext_vector_type(4))) float f32x4;

__device__ __forceinline__ float fast_rcp(float x) { return __builtin_amdgcn_rcpf(x); }

__device__ __forceinline__ float fast_tanh(float x) {
    float ax = fabsf(x);
    float e = __expf(-2.f * ax);
    float r = (1.f - e) * fast_rcp(1.f + e);
    return x >= 0.f ? r : -r;
}

__device__ __forceinline__ unsigned short f2bf(float f) {
    unsigned u = __builtin_bit_cast(unsigned, f);
    unsigned r = (u + 0x7fffu + ((u >> 16) & 1u)) >> 16;
    return (unsigned short)r;
}

__device__ __forceinline__ float bf2f(unsigned short u) {
    return __builtin_bit_cast(float, (unsigned)u << 16);
}

// ---------------- feature transform via MFMA, logits as augmented GEMM columns ----------------
__global__ __launch_bounds__(256) void k_linm(
    const float* __restrict__ x0, const float* __restrict__ W0, const float* __restrict__ b0,
    const float* __restrict__ A00, const float* __restrict__ A01, const float* __restrict__ A02,
    unsigned short* __restrict__ h0,
    float* __restrict__ a00, float* __restrict__ a01, float* __restrict__ a02, int N0, int natt0,
    const float* __restrict__ x1, const float* __restrict__ W1, const float* __restrict__ b1,
    const float* __restrict__ A10, const float* __restrict__ A11, const float* __restrict__ A12,
    unsigned short* __restrict__ h1,
    float* __restrict__ a10, float* __restrict__ a11, float* __restrict__ a12, int N1, int natt1)
{
    const int y = blockIdx.y;
    const float* __restrict__ x  = y ? x1 : x0;
    const float* __restrict__ W  = y ? W1 : W0;
    const float* __restrict__ b  = y ? b1 : b0;
    const float* __restrict__ at0 = y ? A10 : A00;
    const float* __restrict__ at1 = y ? A11 : A01;
    const float* __restrict__ at2 = y ? A12 : A02;
    unsigned short* __restrict__ hb = y ? h1 : h0;
    float* __restrict__ a0 = y ? a10 : a00;
    float* __restrict__ a1 = y ? a11 : a01;
    float* __restrict__ a2 = y ? a12 : a02;
    const int N = y ? N1 : N0;
    const int natt = y ? natt1 : natt0;

    __shared__ unsigned short wtl[NCOL * DIN];  // W^T bf16, chunk-XOR swizzled (20 KB)
    __shared__ float attl[3][FOUT];
    __shared__ float bl[FOUT];
    __shared__ float abias[32];
    const int tid = threadIdx.x;

    if (tid < FOUT) {
        bl[tid] = b[tid];
        attl[0][tid] = at0[tid];
        attl[1][tid] = at1[tid];
        attl[2][tid] = at2[tid];
    }
    __syncthreads();

    for (int idx = tid; idx < DIN * FOUT; idx += 256) {
        int fi = idx >> 7, fo = idx & 127;
        wtl[fo * DIN + (((fi >> 3) ^ (fo & 7)) << 3) + (fi & 7)] = f2bf(W[idx]);
    }
    for (int idx = tid; idx < 2048; idx += 256) {
        int fi = idx >> 5, cs = idx & 31;
        float acc = 0.f;
        if (cs < 24) {
            int a = cs >> 3, hd = cs & 7;
            #pragma unroll
            for (int d = 0; d < 16; d++)
                acc += W[fi * FOUT + hd * 16 + d] * attl[a][hd * 16 + d];
        }
        int fo = 128 + cs;
        wtl[fo * DIN + (((fi >> 3) ^ (fo & 7)) << 3) + (fi & 7)] =
            cs < 24 ? f2bf(acc) : (unsigned short)0;
    }
    if (tid < 32) {
        float acc = 0.f;
        if (tid < 24) {
            int a = tid >> 3, hd = tid & 7;
            #pragma unroll
            for (int d = 0; d < 16; d++) acc += b[hd * 16 + d] * attl[a][hd * 16 + d];
        }
        abias[tid] = acc;
    }
    __syncthreads();

    const int w = tid >> 6, lane = tid & 63;
    const int rt = blockIdx.x * 4 + w;
    if (rt * 16 >= N) return;
    const int r16 = lane & 15, g = lane >> 4;

    int node = rt * 16 + r16;
    if (node >= N) node = N - 1;
    const float* xr = x + (size_t)node * DIN;
    bf16x8 af[2];
    #pragma unroll
    for (int kk = 0; kk < 2; kk++) {
        float4 v0 = *(const float4*)(xr + kk * 32 + g * 8);
        float4 v1 = *(const float4*)(xr + kk * 32 + g * 8 + 4);
        bf16x8 f;
        f[0] = (short)f2bf(v0.x); f[1] = (short)f2bf(v0.y);
        f[2] = (short)f2bf(v0.z); f[3] = (short)f2bf(v0.w);
        f[4] = (short)f2bf(v1.x); f[5] = (short)f2bf(v1.y);
        f[6] = (short)f2bf(v1.z); f[7] = (short)f2bf(v1.w);
        af[kk] = f;
    }

    #pragma unroll
    for (int j = 0; j < 10; j++) {
        const int fo = j * 16 + r16;
        f32x4 acc = {0.f, 0.f, 0.f, 0.f};
        #pragma unroll
        for (int kk = 0; kk < 2; kk++) {
            int c = (kk * 4 + g) ^ (fo & 7);
            bf16x8 bfr = *(bf16x8*)&wtl[fo * DIN + c * 8];
            acc = __builtin_amdgcn_mfma_f32_16x16x32_bf16(af[kk], bfr, acc, 0, 0, 0);
        }
        if (j < 8) {
            float bv = bl[fo];
            #pragma unroll
            for (int r = 0; r < 4; r++) {
                int nr = rt * 16 + g * 4 + r;
                if (nr < N) hb[(size_t)nr * FOUT + fo] = f2bf(acc[r] + bv);
            }
        } else {
            int cs = (j - 8) * 16 + r16;
            if (cs < 24) {
                int a = cs >> 3;
                if (a < natt) {
                    float* __restrict__ ga = a == 0 ? a0 : (a == 1 ? a1 : a2);
                    int hd = cs & 7;
                    float ab = abias[cs];
                    #pragma unroll
                    for (int r = 0; r < 4; r++) {
                        int nr = rt * 16 + g * 4 + r;
                        if (nr < N) ga[(size_t)nr * HH + hd] = acc[r] + ab;
                    }
                }
            }
        }
    }
}

// ---------------- CSR pass 1: per-(type,bin,chunk) histogram, dense store, NO global atomics ----
// Grid mapping bx = chunk*nbp + tb (nbp%8==0) pins each (type,bin) to one XCD.
__global__ __launch_bounds__(512) void k_hist(
    const int* __restrict__ e0, int E0, const int* __restrict__ e1, int E1,
    int* __restrict__ chist, int nbin, int nbp)
{
    const int bx = blockIdx.x;
    const int chunk = bx / nbp;
    const int tb = bx % nbp;
    if (tb >= 2 * nbin) return;
    const bool type = tb >= nbin;
    const int bin = type ? tb - nbin : tb;
    const int* __restrict__ e = type ? e1 : e0;
    const int E = type ? E1 : E0;
    const int lo = bin * HR;

    __shared__ int hist[HR];
    for (int j = threadIdx.x; j < HR; j += 512) hist[j] = 0;
    __syncthreads();

    const int per = (E + CHUNKN - 1) / CHUNKN;
    const int s0 = chunk * per;
    const int s1 = s0 + per < E ? s0 + per : E;
    for (int i = s0 + threadIdx.x; i < s1; i += 512) {
        unsigned r = (unsigned)(e[E + i] - lo);
        if (r < HR) atomicAdd(&hist[r], 1);   // LDS atomic only
    }
    __syncthreads();
    int* __restrict__ out = chist + ((size_t)tb * CHUNKN + chunk) * HR;
    for (int j = threadIdx.x; j < HR; j += 512) out[j] = hist[j];
}

// ---------------- CSR pass 2: deg from chunk-hists, block scan, per-chunk exclusive offsets ----
__global__ __launch_bounds__(256) void k_scan_block2(
    int* __restrict__ chist,
    int* __restrict__ out0, int* __restrict__ bs0,
    int* __restrict__ out1, int* __restrict__ bs1,
    int* __restrict__ d0, int* __restrict__ d1,
    int n, int nbin)
{
    const int type = blockIdx.y;
    int* __restrict__ out = type ? out1 : out0;
    int* __restrict__ bsum = type ? bs1 : bs0;
    int* __restrict__ deg = type ? d1 : d0;
    __shared__ int s[256];
    const int tid = threadIdx.x;
    const int i = blockIdx.x * 256 + tid;
    int v = 0;
    int hvals[CHUNKN];
    int* hp = nullptr;
    if (i < n) {
        const int bin = i / HR, jr = i & (HR - 1);
        hp = chist + ((size_t)(type * nbin + bin) * CHUNKN) * HR + jr;
        #pragma unroll
        for (int c = 0; c < CHUNKN; c++) { hvals[c] = hp[c * HR]; v += hvals[c]; }
    }
    s[tid] = v; __syncthreads();
    for (int off = 1; off < 256; off <<= 1) {
        int t = tid >= off ? s[tid - off] : 0;
        __syncthreads();
        s[tid] += t;
        __syncthreads();
    }
    if (i < n) {
        out[i] = s[tid] - v;          // exclusive rowptr (block-prefix added later)
        deg[i] = v;
        int run = 0;                  // exclusive prefix over chunks -> choff
        #pragma unroll
        for (int c = 0; c < CHUNKN; c++) { int t = hvals[c]; hp[c * HR] = run; run += t; }
    }
    if (tid == 255) bsum[blockIdx.x] = s[255];
}

// ---------------- CSR pass 2b: add block prefix (each block self-reduces raw bsum) ----------------
__global__ __launch_bounds__(256) void k_scan_add2(
    int* __restrict__ o0, const int* __restrict__ b0,
    int* __restrict__ o1, const int* __restrict__ b1, int n)
{
    int* __restrict__ out = blockIdx.y ? o1 : o0;
    const int* __restrict__ bsum = blockIdx.y ? b1 : b0;
    __shared__ int s[256];
    const int tid = threadIdx.x;
    const int bx = blockIdx.x;
    int acc = 0;
    for (int j = tid; j < bx; j += 256) acc += bsum[j];
    s[tid] = acc; __syncthreads();
    for (int w = 128; w > 0; w >>= 1) {
        if (tid < w) s[tid] += s[tid + w];
        __syncthreads();
    }
    const int pre = s[0];
    const int i = bx * 256 + tid;
    if (i < n) out[i] += pre;
}

// ---------------- CSR pass 3: scatter; cnt initialized to choff so atomicAdd yields position ----
__global__ __launch_bounds__(512) void k_scatb(
    const int* __restrict__ e0, int E0, const int* __restrict__ rp0, int* __restrict__ sl0,
    const int* __restrict__ e1, int E1, const int* __restrict__ rp1, int* __restrict__ sl1,
    const int* __restrict__ chist, int nbin, int nbp)
{
    const int bx = blockIdx.x;
    const int chunk = bx / nbp;
    const int tb = bx % nbp;
    if (tb >= 2 * nbin) return;
    const bool type = tb >= nbin;
    const int bin = type ? tb - nbin : tb;
    const int* __restrict__ e = type ? e1 : e0;
    const int E = type ? E1 : E0;
    const int* __restrict__ rp = type ? rp1 : rp0;
    int* __restrict__ sl = type ? sl1 : sl0;
    const int lo = bin * HR;

    __shared__ int cnt[HR];   // 32 KB: starts at choff, atomicAdd returns choff+rank
    const int* __restrict__ cop = chist + ((size_t)tb * CHUNKN + chunk) * HR;
    for (int j = threadIdx.x; j < HR; j += 512) cnt[j] = cop[j];
    __syncthreads();

    const int per = (E + CHUNKN - 1) / CHUNKN;
    const int s0 = chunk * per;
    const int s1 = s0 + per < E ? s0 + per : E;
    for (int i = s0 + threadIdx.x; i < s1; i += 512) {
        int dst = e[E + i];
        unsigned r = (unsigned)(dst - lo);
        if (r < HR) {
            int pos = rp[dst] + atomicAdd(&cnt[r], 1);   // LDS atomic only
            sl[pos] = e[i];
        }
    }
}

// ---------------- aggregation: 32 lanes per dst, bf16 gathers, bf16 o output ----------------
__global__ __launch_bounds__(256) void k_agg2(
    const int* __restrict__ sl0, const int* __restrict__ rp0, const int* __restrict__ dg0,
    const unsigned short* __restrict__ xb0, const float* __restrict__ as0, const float* __restrict__ ad0,
    unsigned short* __restrict__ oo0,
    const int* __restrict__ sl1, const int* __restrict__ rp1, const int* __restrict__ dg1,
    const unsigned short* __restrict__ xb1, const float* __restrict__ as1, const float* __restrict__ ad1,
    unsigned short* __restrict__ oo1,
    int N)
{
    const bool m = blockIdx.y;
    const int* __restrict__ sl = m ? sl1 : sl0;
    const int* __restrict__ rp = m ? rp1 : rp0;
    const int* __restrict__ dg = m ? dg1 : dg0;
    const unsigned short* __restrict__ xb = m ? xb1 : xb0;
    const float* __restrict__ as_ = m ? as1 : as0;
    const float* __restrict__ ad_ = m ? ad1 : ad0;
    unsigned short* __restrict__ oo = m ? oo1 : oo0;

    const int t = blockIdx.x * 256 + threadIdx.x;
    const int dst = t >> 5;
    if (dst >= N) return;
    const int lane = t & 31;
    const int h = lane >> 2;
    const int d = dg[dst];
    const int base = rp[dst];
    const float adv = ad_[(size_t)dst * HH + h];
    float acc0 = 0.f, acc1 = 0.f, acc2 = 0.f, acc3 = 0.f;
    float wsum = 0.f;
    int src_next = d > 0 ? sl[base] : 0;
    for (int k = 0; k < d; k++) {
        int src = src_next;
        if (k + 1 < d) src_next = sl[base + k + 1];
        float a = as_[(size_t)src * HH + h] + adv;
        a = a > 0.f ? a : NSLOPE * a;
        float wv = __expf(a);
        uint2 xv = *(const uint2*)(xb + (size_t)src * FOUT + lane * 4);
        acc0 = fmaf(wv, bf2f((unsigned short)(xv.x & 0xffff)), acc0);
        acc1 = fmaf(wv, bf2f((unsigned short)(xv.x >> 16)), acc1);
        acc2 = fmaf(wv, bf2f((unsigned short)(xv.y & 0xffff)), acc2);
        acc3 = fmaf(wv, bf2f((unsigned short)(xv.y >> 16)), acc3);
        wsum += wv;
    }
    float inv = fast_rcp(wsum + 1e-16f);
    unsigned p0 = ((unsigned)f2bf(fmaxf(acc1 * inv, 0.f)) << 16) | f2bf(fmaxf(acc0 * inv, 0.f));
    unsigned p1 = ((unsigned)f2bf(fmaxf(acc3 * inv, 0.f)) << 16) | f2bf(fmaxf(acc2 * inv, 0.f));
    *(uint2*)(oo + (size_t)dst * FOUT + lane * 4) = make_uint2(p0, p1);
}

// ---------------- semantic score + z = o @ lin_w (augmented columns 128-129) ----------------
__global__ __launch_bounds__(256) void k_sem(
    const unsigned short* __restrict__ o1p, const unsigned short* __restrict__ o2p,
    const float* __restrict__ kw, const float* __restrict__ kb,
    const float* __restrict__ q, const float* __restrict__ lw,
    float* __restrict__ score, float* __restrict__ z1p, float* __restrict__ z2p, int N)
{
    __shared__ unsigned short kwl[SEMR * FOUT];  // kw^T (+2 lin_w rows) bf16, chunk-XOR swizzled
    __shared__ float red[256];
    const int tid = threadIdx.x;

    for (int idx = tid; idx < FOUT * FOUT; idx += 256) {
        int fi = idx >> 7, fo = idx & 127;
        int c = (fi >> 3) ^ (fo & 15);
        kwl[fo * 128 + c * 8 + (fi & 7)] = f2bf(kw[idx]);
    }
    for (int idx = tid; idx < (SEMR - FOUT) * FOUT; idx += 256) {
        int fi = idx & 127, fr = idx >> 7;      // fr 0..15
        int fo = FOUT + fr;
        int c = (fi >> 3) ^ (fo & 15);
        float v = fr == 0 ? lw[fi * 2] : (fr == 1 ? lw[fi * 2 + 1] : 0.f);
        kwl[fo * 128 + c * 8 + (fi & 7)] = f2bf(v);
    }
    __syncthreads();

    const int lane = tid & 63;
    const int w = tid >> 6;
    const int n0 = blockIdx.x * 256 + w * 64;
    const int r16 = lane & 15;
    const int g = lane >> 4;

    float qv[8], kbv[8];
    #pragma unroll
    for (int j = 0; j < 8; j++) { qv[j] = q[j * 16 + r16]; kbv[j] = kb[j * 16 + r16]; }

    for (int m = 0; m < 2; m++) {
        const unsigned short* __restrict__ o = m ? o2p : o1p;
        float* __restrict__ zp = m ? z2p : z1p;
        bf16x8 afrag[4][4];
        #pragma unroll
        for (int i = 0; i < 4; i++) {
            int node = n0 + i * 16 + r16;
            if (node > N - 1) node = N - 1;
            const unsigned short* rowp = o + (size_t)node * FOUT + g * 8;
            #pragma unroll
            for (int kk = 0; kk < 4; kk++)
                afrag[i][kk] = *(const bf16x8*)(rowp + kk * 32);
        }

        float part = 0.f;
        #pragma unroll
        for (int j = 0; j < 9; j++) {
            const int fo = j * 16 + r16;
            f32x4 acc0 = {0.f,0.f,0.f,0.f}, acc1 = {0.f,0.f,0.f,0.f};
            f32x4 acc2 = {0.f,0.f,0.f,0.f}, acc3 = {0.f,0.f,0.f,0.f};
            #pragma unroll
            for (int kk = 0; kk < 4; kk++) {
                int c = (kk * 4 + g) ^ (fo & 15);
                bf16x8 bfr = *(bf16x8*)&kwl[fo * 128 + c * 8];
                acc0 = __builtin_amdgcn_mfma_f32_16x16x32_bf16(afrag[0][kk], bfr, acc0, 0, 0, 0);
                acc1 = __builtin_amdgcn_mfma_f32_16x16x32_bf16(afrag[1][kk], bfr, acc1, 0, 0, 0);
                acc2 = __builtin_amdgcn_mfma_f32_16x16x32_bf16(afrag[2][kk], bfr, acc2, 0, 0, 0);
                acc3 = __builtin_amdgcn_mfma_f32_16x16x32_bf16(afrag[3][kk], bfr, acc3, 0, 0, 0);
            }
            #pragma unroll
            for (int i = 0; i < 4; i++) {
                f32x4 a = i == 0 ? acc0 : (i == 1 ? acc1 : (i == 2 ? acc2 : acc3));
                if (j < 8) {
                    #pragma unroll
                    for (int r = 0; r < 4; r++) {
                        int node = n0 + i * 16 + g * 4 + r;
                        if (node < N) part += fast_tanh(a[r] + kbv[j]) * qv[j];
                    }
                } else if (r16 < 2) {          // cols 128,129 = z0,z1
                    #pragma unroll
                    for (int r = 0; r < 4; r++) {
                        int node = n0 + i * 16 + g * 4 + r;
                        if (node < N) zp[(size_t)node * 2 + r16] = a[r];
                    }
                }
            }
        }
        red[tid] = part;
        __syncthreads();
        for (int s2 = 128; s2 > 0; s2 >>= 1) {
            if (tid < s2) red[tid] += red[tid + s2];
            __syncthreads();
        }
        if (tid == 0) atomicAdd(score + m, red[0]);
        __syncthreads();
    }
}

// ---------------- final: out = attn0*z1 + attn1*z2 + lb (z precomputed in k_sem) ----------------
__global__ __launch_bounds__(256) void k_final(
    const float* __restrict__ z1, const float* __restrict__ z2,
    const float* __restrict__ score, float invN,
    const float* __restrict__ lb, float* __restrict__ out, int N)
{
    __shared__ float attns[2];
    const int tid = threadIdx.x;
    if (tid == 0) {
        float s0 = score[0] * invN, s1 = score[1] * invN;
        float mm = fmaxf(s0, s1);
        float e0 = __expf(s0 - mm), e1 = __expf(s1 - mm);
        float inv = 1.f / (e0 + e1);
        attns[0] = e0 * inv;
        attns[1] = e1 * inv;
    }
    __syncthreads();
    const int n = blockIdx.x * 256 + tid;
    if (n >= N) return;
    const float a0 = attns[0], a1 = attns[1];
    float2 v1 = *(const float2*)(z1 + (size_t)n * 2);
    float2 v2 = *(const float2*)(z2 + (size_t)n * 2);
    float2 o;
    o.x = a0 * v1.x + a1 * v2.x + lb[0];
    o.y = a0 * v1.y + a1 * v2.y + lb[1];
    *(float2*)(out + (size_t)n * 2) = o;
}

extern "C" void kernel_launch(void* const* d_in, const int* in_sizes, int n_in,
                              void* d_out, int out_size, void* d_ws, size_t ws_size,
                              hipStream_t stream)
{
    const float* x_subj = (const float*)d_in[0];
    const float* x_chan = (const float*)d_in[1];
    const int*   e_cs   = (const int*)d_in[2];
    const int*   e_ss   = (const int*)d_in[3];
    const float* W_s    = (const float*)d_in[4];
    const float* b_s    = (const float*)d_in[5];
    const float* W_c    = (const float*)d_in[6];
    const float* b_c    = (const float*)d_in[7];
    const float* att_src_cs = (const float*)d_in[8];
    const float* att_dst_cs = (const float*)d_in[9];
    const float* att_src_ss = (const float*)d_in[10];
    const float* att_dst_ss = (const float*)d_in[11];
    const float* k_w  = (const float*)d_in[12];
    const float* k_b  = (const float*)d_in[13];
    const float* q    = (const float*)d_in[14];
    const float* lw   = (const float*)d_in[15];
    const float* lb   = (const float*)d_in[16];

    const int Ns  = in_sizes[0] / DIN;
    const int Nc  = in_sizes[1] / DIN;
    const int Ecs = in_sizes[2] / 2;
    const int Ess = in_sizes[3] / 2;

    const int nbin = (Ns + HR - 1) / HR;
    const int nbp = ((2 * nbin + 7) / 8) * 8;   // pad (type,bin) space to mult of 8 -> XCD pin

    // ---- workspace layout (all chunks 16B-aligned) ----
    char* p = (char*)d_ws;
    unsigned short* hbf_s = (unsigned short*)p; p += (size_t)Ns * FOUT * 2;
    unsigned short* hbf_c = (unsigned short*)p; p += (size_t)Nc * FOUT * 2;
    float* a_src_cs_ = (float*)p; p += (size_t)Nc * HH * 4;
    float* a_dst_cs_ = (float*)p; p += (size_t)Ns * HH * 4;
    float* a_src_ss_ = (float*)p; p += (size_t)Ns * HH * 4;
    float* a_dst_ss_ = (float*)p; p += (size_t)Ns * HH * 4;
    unsigned short* o1 = (unsigned short*)p; p += (size_t)Ns * FOUT * 2;
    unsigned short* o2 = (unsigned short*)p; p += (size_t)Ns * FOUT * 2;
    int* srclist_cs  = (int*)p;   p += (size_t)Ecs * 4;
    int* srclist_ss  = (int*)p;   p += (size_t)Ess * 4;
    int* rowptr_cs   = (int*)p;   p += (size_t)Ns * 4;
    int* rowptr_ss   = (int*)p;   p += (size_t)Ns * 4;
    int* deg_cs      = (int*)p;   p += (size_t)Ns * 4;
    int* deg_ss      = (int*)p;   p += (size_t)Ns * 4;
    float* z1        = (float*)p; p += (size_t)Ns * 2 * 4;
    float* z2        = (float*)p; p += (size_t)Ns * 2 * 4;
    int* bsum0       = (int*)p;   p += 2048;
    int* bsum1       = (int*)p;   p += 2048;
    int* chist       = (int*)p;   p += (size_t)2 * nbin * CHUNKN * HR * 4;  // ~17 MB
    // zeroed region: score only
    float* score = (float*)p; p += 16;   // [s0, s1]
    hipMemsetAsync(score, 0, 16, stream);

    const int nbN = (Ns + 255) / 256;
    const int Nmax = Ns > Nc ? Ns : Nc;
    const int gx_lin = ((Nmax + 15) / 16 + 3) / 4;

    // feature transforms + logits (both node types), one dispatch
    k_linm<<<dim3(gx_lin, 2), dim3(256), 0, stream>>>(
        x_subj, W_s, b_s, att_dst_cs, att_src_ss, att_dst_ss,
        hbf_s, a_dst_cs_, a_src_ss_, a_dst_ss_, Ns, 3,
        x_chan, W_c, b_c, att_src_cs, att_src_cs, att_src_cs,
        hbf_c, a_src_cs_, a_src_cs_, a_src_cs_, Nc, 1);

    // CSR build, atomic-free (per-chunk histograms + LDS rank scatter), XCD-pinned bins
    k_hist<<<dim3(nbp * CHUNKN), dim3(512), 0, stream>>>(
        e_cs, Ecs, e_ss, Ess, chist, nbin, nbp);
    k_scan_block2<<<dim3(nbN, 2), dim3(256), 0, stream>>>(
        chist, rowptr_cs, bsum0, rowptr_ss, bsum1, deg_cs, deg_ss, Ns, nbin);
    k_scan_add2<<<dim3(nbN, 2), dim3(256), 0, stream>>>(rowptr_cs, bsum0, rowptr_ss, bsum1, Ns);
    k_scatb<<<dim3(nbp * CHUNKN), dim3(512), 0, stream>>>(
        e_cs, Ecs, rowptr_cs, srclist_cs,
        e_ss, Ess, rowptr_ss, srclist_ss, chist, nbin, nbp);

    // aggregation (fused softmax-normalize + relu), both metapaths
    k_agg2<<<dim3(((size_t)Ns * 32 + 255) / 256, 2), dim3(256), 0, stream>>>(
        srclist_cs, rowptr_cs, deg_cs, hbf_c, a_src_cs_, a_dst_cs_, o1,
        srclist_ss, rowptr_ss, deg_ss, hbf_s, a_src_ss_, a_dst_ss_, o2, Ns);

    // semantic attention (+ z = o @ lin_w) + trivial final combine
    k_sem<<<dim3(nbN), dim3(256), 0, stream>>>(
        o1, o2, k_w, k_b, q, lw, score, z1, z2, Ns);
    k_final<<<dim3(nbN), dim3(256), 0, stream>>>(
        z1, z2, score, 1.f / (float)Ns, lb, (float*)d_out, Ns);
}